// Round 2
// baseline (448.151 us; speedup 1.0000x reference)
//
#include <hip/hip_runtime.h>

typedef __bf16 bfrag __attribute__((ext_vector_type(8)));
typedef float f32x4 __attribute__((ext_vector_type(4)));

__device__ __forceinline__ unsigned short f2bf(float f) {
  unsigned u = __float_as_uint(f);
  u = (u + 0x7fffu + ((u >> 16) & 1u)) >> 16;
  return (unsigned short)u;
}
__device__ __forceinline__ float bflo(unsigned u) { return __uint_as_float(u << 16); }
__device__ __forceinline__ float bfhi(unsigned u) { return __uint_as_float(u & 0xffff0000u); }

// ---------------- weight prep: FRAGMENT-MAJOR layouts ----------------
// WcatF[((cb*8 + cB)*4 + ks)*512 + lane*8 + j]: B-frag for in_proj block cb,
//   col-block cB, k-step ks; lane=(quad*16+mr) holds row cB*16+mr, k=ks*32+quad*8+j.
// W2F[((cB*4 + kc)*2 + ks2)*512 + lane*8 + j]: same for [W2 | W00] (K=256).
// cvec = conv_b + conv_w01 @ out_proj_b
__global__ void k_prep(const float* __restrict__ in_proj_w,
                       const float* __restrict__ conv_w,
                       const float* __restrict__ out_proj_w,
                       const float* __restrict__ out_proj_b,
                       const float* __restrict__ conv_b,
                       unsigned short* __restrict__ WcatF,
                       unsigned short* __restrict__ W2F,
                       float* __restrict__ cvec) {
  int b = blockIdx.x, t = threadIdx.x;
  if (b < 384) {
    unsigned short v = f2bf(in_proj_w[b * 128 + t]);
    int cb = b >> 7, r7 = b & 127;
    int cB = r7 >> 4, mr = r7 & 15;
    int ks = t >> 5, quad = (t >> 3) & 3, j = t & 7;
    WcatF[(((cb * 8 + cB) * 4 + ks) << 9) + (quad * 16 + mr) * 8 + j] = v;
  } else {
    int c = b - 384;  // output channel (B-row)
    int cB = c >> 4, mr = c & 15;
    float s = 0.f;
    for (int k = 0; k < 128; ++k)
      s += conv_w[(c * 128 + k) * 2 + 1] * out_proj_w[k * 128 + t];
    {  // K = t (W2 part)
      int kc = t >> 6, ks2 = (t >> 5) & 1, quad = (t >> 3) & 3, j = t & 7;
      W2F[(((cB * 4 + kc) * 2 + ks2) << 9) + (quad * 16 + mr) * 8 + j] = f2bf(s);
    }
    {  // K = 128 + t (W00 part)
      int K = 128 + t;
      int kc = K >> 6, ks2 = (K >> 5) & 1, quad = (K >> 3) & 3, j = K & 7;
      W2F[(((cB * 4 + kc) * 2 + ks2) << 9) + (quad * 16 + mr) * 8 + j] =
          f2bf(conv_w[(c * 128 + t) * 2]);
    }
    if (t == 0) {
      float cs = conv_b[c];
      for (int k = 0; k < 128; ++k)
        cs += conv_w[(c * 128 + k) * 2 + 1] * out_proj_b[k];
      cvec[c] = cs;
    }
  }
}

// ---------------- fused QKV GEMM: ZERO barriers, all frags direct ----------
// Q -> Qb (row=128 ushort). K,V -> KVb interleaved (row=256 ushort: K|V).
__global__ __launch_bounds__(256, 4) void k_gemm_qkv(
    const float* __restrict__ x, const unsigned short* __restrict__ WcatF,
    const float* __restrict__ in_proj_b, unsigned short* __restrict__ Qb,
    unsigned short* __restrict__ KVb, int M) {
  __shared__ unsigned short se[4][32 * 72];  // wave-private transpose, 18.4 KB total
  const int m0 = blockIdx.x * 128;
  const int t = threadIdx.x;
  const int w = t >> 6, lane = t & 63, quad = lane >> 4, mr = lane & 15;
  unsigned short* sew = se[w];

  // A fragments direct from x: lane (quad,mr), rows w*32+r*16+mr, k=ks*32+quad*8
  bfrag af[4][2];
#pragma unroll
  for (int ks = 0; ks < 4; ++ks)
#pragma unroll
    for (int r = 0; r < 2; ++r) {
      int row = m0 + w * 32 + r * 16 + mr;
      union { unsigned short s[8]; bfrag f; } u;
      if (row < M) {
        const float4* p =
            reinterpret_cast<const float4*>(&x[(size_t)row * 128 + ks * 32 + quad * 8]);
        float4 v0 = p[0], v1 = p[1];
        u.s[0] = f2bf(v0.x); u.s[1] = f2bf(v0.y); u.s[2] = f2bf(v0.z); u.s[3] = f2bf(v0.w);
        u.s[4] = f2bf(v1.x); u.s[5] = f2bf(v1.y); u.s[6] = f2bf(v1.z); u.s[7] = f2bf(v1.w);
      } else {
#pragma unroll
        for (int i = 0; i < 8; ++i) u.s[i] = 0;
      }
      af[ks][r] = u.f;
    }

#pragma unroll
  for (int cb = 0; cb < 3; ++cb) {
    unsigned short* dst = (cb == 0) ? Qb : KVb;
    const int ldst = (cb == 0) ? 128 : 256;
    const int cb_off = (cb == 2) ? 128 : 0;
#pragma unroll
    for (int half = 0; half < 2; ++half) {
      f32x4 acc[2][4];
#pragma unroll
      for (int r = 0; r < 2; ++r)
#pragma unroll
        for (int c = 0; c < 4; ++c) acc[r][c] = (f32x4){0.f, 0.f, 0.f, 0.f};
#pragma unroll
      for (int ks = 0; ks < 4; ++ks)
#pragma unroll
        for (int c = 0; c < 4; ++c) {
          union { uint4 v; bfrag f; } u;
          u.v = *reinterpret_cast<const uint4*>(
              &WcatF[(((cb * 8 + half * 4 + c) * 4 + ks) << 9) + lane * 8]);
          acc[0][c] = __builtin_amdgcn_mfma_f32_16x16x32_bf16(af[ks][0], u.f, acc[0][c], 0, 0, 0);
          acc[1][c] = __builtin_amdgcn_mfma_f32_16x16x32_bf16(af[ks][1], u.f, acc[1][c], 0, 0, 0);
        }
      // wave-private epilogue: 32 rows x 64 cols -> bf16 -> coalesced stores
      const float* bias = in_proj_b + cb * 128 + half * 64;
#pragma unroll
      for (int r = 0; r < 2; ++r)
#pragma unroll
        for (int c = 0; c < 4; ++c) {
          float bv = bias[c * 16 + mr];
#pragma unroll
          for (int g = 0; g < 4; ++g)
            sew[(r * 16 + quad * 4 + g) * 72 + c * 16 + mr] = f2bf(acc[r][c][g] + bv);
        }
#pragma unroll
      for (int i = 0; i < 4; ++i) {
        int ch = i * 64 + lane;  // 256 chunks: 32 rows x 8 x 16B
        int row = ch >> 3, cp = ch & 7;
        int grow = m0 + w * 32 + row;
        if (grow < M) {
          uint4 v = *reinterpret_cast<const uint4*>(&sew[row * 72 + cp * 8]);
          *reinterpret_cast<uint4*>(
              &dst[(size_t)grow * ldst + cb_off + half * 64 + cp * 8]) = v;
        }
      }
    }
  }
}

// ---------------- FUSED attn + GEMM2: O never touches HBM ------------------
// Wave w: attention for rows m0+w*32+[0,32) -> wave-private LDS O tile
// (stride 136 ushorts = 272 B; A-frag ds_read_b128 bank starts 4*((mr+quad)%8)
//  -> 8 classes x 8 lanes = conflict-free). Then GEMM2 A-frags (kc<2) read
// from LDS; x part (kc>=2) from global. Epilogue reuses the O tile as fp32
// scratch (one __syncthreads orders the type-punned LDS reuse).
__global__ __launch_bounds__(256, 4) void k_fused(
    const unsigned short* __restrict__ Qb, const unsigned short* __restrict__ KVb,
    const int* __restrict__ fn, const float* __restrict__ x,
    const unsigned short* __restrict__ W2F, const float* __restrict__ cvec,
    float* __restrict__ out, int M) {
  __shared__ unsigned short Os[4][32 * 136];  // 34.8 KB -> 4 blocks/CU
  const int m0 = blockIdx.x * 128;
  const int t = threadIdx.x;
  const int w = t >> 6, lane = t & 63, quad = lane >> 4, mr = lane & 15;
  unsigned short* Ow = Os[w];

  // ---- phase 1: attention (identical math to k_attn) ----
  {
    const float scale = 0.17677669529663687f;  // 1/sqrt(32)
    const int l5 = lane & 31;
    for (int ri = 0; ri < 32; ++ri) {
      const int n = m0 + w * 32 + ri;
      if (n >= M) break;  // wave-uniform; tail rows leave garbage (never stored)
      uint2 qp = *reinterpret_cast<const uint2*>(&Qb[(size_t)n * 128 + 4 * l5]);
      float q0 = bflo(qp.x), q1 = bfhi(qp.x), q2 = bflo(qp.y), q3 = bfhi(qp.y);
      int idx[8];
#pragma unroll
      for (int j = 0; j < 8; ++j) idx[j] = fn[n * 9 + 1 + j];
      float o0 = 0.f, o1 = 0.f, o2 = 0.f, o3 = 0.f, sum = 0.f;
#pragma unroll
      for (int j = 0; j < 8; ++j) {
        bool valid = idx[j] < M;
        int id = valid ? idx[j] : 0;
        uint2 kv = *reinterpret_cast<const uint2*>(&KVb[(size_t)id * 256 + 4 * lane]);
        float a0 = bflo(kv.x), a1 = bfhi(kv.x), a2 = bflo(kv.y), a3 = bfhi(kv.y);
        float p = q0 * a0 + q1 * a1 + q2 * a2 + q3 * a3;
        p += __shfl_xor(p, 1);
        p += __shfl_xor(p, 2);
        p += __shfl_xor(p, 4);              // full head dot in 8-lane groups of K half
        float pu = __shfl_xor(p, 32);       // broadcast to V half
        float sv = (lane >= 32) ? pu : p;
        float s = valid ? sv * scale : -1e30f;
        float e = __expf(s);                // |s| << 88, no max-pass needed
        sum += e;
        o0 += e * a0; o1 += e * a1; o2 += e * a2; o3 += e * a3;
      }
      float inv = 1.f / sum;
      if (lane >= 32) {
        union { unsigned short s[4]; uint2 u; } pk;
        pk.s[0] = f2bf(o0 * inv); pk.s[1] = f2bf(o1 * inv);
        pk.s[2] = f2bf(o2 * inv); pk.s[3] = f2bf(o3 * inv);
        *reinterpret_cast<uint2*>(&Ow[ri * 136 + 4 * l5]) = pk.u;  // 256B contig/wave
      }
    }
  }
  // No barrier needed: Ow is produced and consumed by the SAME wave.

  // ---- phase 2: out = [O | x] @ [W2 | W00]^T + cvec ----
  f32x4 acc[2][8];
#pragma unroll
  for (int r = 0; r < 2; ++r)
#pragma unroll
    for (int c = 0; c < 8; ++c) acc[r][c] = (f32x4){0.f, 0.f, 0.f, 0.f};

#pragma unroll
  for (int kc = 0; kc < 4; ++kc) {
    bfrag af[2][2];
#pragma unroll
    for (int ks2 = 0; ks2 < 2; ++ks2)
#pragma unroll
      for (int r = 0; r < 2; ++r) {
        if (kc < 2) {  // O part from wave-private LDS
          union { uint4 v; bfrag f; } u;
          u.v = *reinterpret_cast<const uint4*>(
              &Ow[(r * 16 + mr) * 136 + kc * 64 + ks2 * 32 + quad * 8]);
          af[ks2][r] = u.f;
        } else {  // x part from global
          int row = m0 + w * 32 + r * 16 + mr;
          union { unsigned short s[8]; bfrag f; } u;
          if (row < M) {
            const float4* p = reinterpret_cast<const float4*>(
                &x[(size_t)row * 128 + (kc - 2) * 64 + ks2 * 32 + quad * 8]);
            float4 v0 = p[0], v1 = p[1];
            u.s[0] = f2bf(v0.x); u.s[1] = f2bf(v0.y); u.s[2] = f2bf(v0.z); u.s[3] = f2bf(v0.w);
            u.s[4] = f2bf(v1.x); u.s[5] = f2bf(v1.y); u.s[6] = f2bf(v1.z); u.s[7] = f2bf(v1.w);
          } else {
#pragma unroll
            for (int i = 0; i < 8; ++i) u.s[i] = 0;
          }
          af[ks2][r] = u.f;
        }
      }
#pragma unroll
    for (int ks2 = 0; ks2 < 2; ++ks2)
#pragma unroll
      for (int c = 0; c < 8; ++c) {
        union { uint4 v; bfrag f; } u;
        u.v = *reinterpret_cast<const uint4*>(
            &W2F[(((c * 4 + kc) * 2 + ks2) << 9) + lane * 8]);
        acc[0][c] = __builtin_amdgcn_mfma_f32_16x16x32_bf16(af[ks2][0], u.f, acc[0][c], 0, 0, 0);
        acc[1][c] = __builtin_amdgcn_mfma_f32_16x16x32_bf16(af[ks2][1], u.f, acc[1][c], 0, 0, 0);
      }
  }

  __syncthreads();  // drain lgkm: order Ow(b16) reads before fp32 scratch reuse
  float* sfw = reinterpret_cast<float*>(Ow);  // 4.6 KB needed, 8.7 KB available
#pragma unroll
  for (int p = 0; p < 4; ++p) {
#pragma unroll
    for (int cc = 0; cc < 2; ++cc) {
      int c = p * 2 + cc;
      float cv = cvec[c * 16 + mr];
#pragma unroll
      for (int r = 0; r < 2; ++r)
#pragma unroll
        for (int g = 0; g < 4; ++g)
          sfw[(r * 16 + quad * 4 + g) * 36 + cc * 16 + mr] = acc[r][c][g] + cv;
    }
#pragma unroll
    for (int i = 0; i < 4; ++i) {
      int ch = i * 64 + lane;  // 256 chunks: 32 rows x 8 float4
      int row = ch >> 3, c4 = ch & 7;
      int grow = m0 + w * 32 + row;
      if (grow < M) {
        float4 v = *reinterpret_cast<const float4*>(&sfw[row * 36 + c4 * 4]);
        *reinterpret_cast<float4*>(&out[(size_t)grow * 128 + p * 32 + c4 * 4]) = v;
      }
    }
  }
}

// ---------------- legacy fallback kernels (workspace too small) ------------
__global__ __launch_bounds__(256) void k_attn(
    const unsigned short* __restrict__ Qb, const unsigned short* __restrict__ KVb,
    const int* __restrict__ fn, unsigned short* __restrict__ Ob, int M) {
  int w = threadIdx.x >> 6, lane = threadIdx.x & 63;
  int n = blockIdx.x * 4 + w;
  if (n >= M) return;
  const float scale = 0.17677669529663687f;  // 1/sqrt(32)
  const int l5 = lane & 31;
  uint2 qp = *reinterpret_cast<const uint2*>(&Qb[(size_t)n * 128 + 4 * l5]);
  float q0 = bflo(qp.x), q1 = bfhi(qp.x), q2 = bflo(qp.y), q3 = bfhi(qp.y);
  int idx[8];
#pragma unroll
  for (int j = 0; j < 8; ++j) idx[j] = fn[n * 9 + 1 + j];
  float o0 = 0.f, o1 = 0.f, o2 = 0.f, o3 = 0.f, sum = 0.f;
#pragma unroll
  for (int j = 0; j < 8; ++j) {
    bool valid = idx[j] < M;
    int id = valid ? idx[j] : 0;
    uint2 kv = *reinterpret_cast<const uint2*>(&KVb[(size_t)id * 256 + 4 * lane]);
    float a0 = bflo(kv.x), a1 = bfhi(kv.x), a2 = bflo(kv.y), a3 = bfhi(kv.y);
    float p = q0 * a0 + q1 * a1 + q2 * a2 + q3 * a3;
    p += __shfl_xor(p, 1);
    p += __shfl_xor(p, 2);
    p += __shfl_xor(p, 4);
    float pu = __shfl_xor(p, 32);
    float sf = (lane >= 32) ? pu : p;
    float s = valid ? sf * scale : -1e30f;
    float e = __expf(s);
    sum += e;
    o0 += e * a0; o1 += e * a1; o2 += e * a2; o3 += e * a3;
  }
  float inv = 1.f / sum;
  if (lane >= 32) {
    union { unsigned short s[4]; uint2 u; } p;
    p.s[0] = f2bf(o0 * inv); p.s[1] = f2bf(o1 * inv);
    p.s[2] = f2bf(o2 * inv); p.s[3] = f2bf(o3 * inv);
    *reinterpret_cast<uint2*>(&Ob[(size_t)n * 128 + 4 * l5]) = p.u;
  }
}

__global__ __launch_bounds__(256, 4) void k_gemm_out(
    const unsigned short* __restrict__ Ob, const float* __restrict__ x,
    const unsigned short* __restrict__ W2F, const float* __restrict__ cvec,
    float* __restrict__ out, int M) {
  __shared__ float sf[4][32 * 36];  // wave-private fp32 transpose, 18.4 KB total
  const int m0 = blockIdx.x * 128;
  const int t = threadIdx.x;
  const int w = t >> 6, lane = t & 63, quad = lane >> 4, mr = lane & 15;
  float* sfw = sf[w];

  f32x4 acc[2][8];
#pragma unroll
  for (int r = 0; r < 2; ++r)
#pragma unroll
    for (int c = 0; c < 8; ++c) acc[r][c] = (f32x4){0.f, 0.f, 0.f, 0.f};

#pragma unroll
  for (int kc = 0; kc < 4; ++kc) {
    bfrag af[2][2];  // A frags for this K-chunk, direct from global
#pragma unroll
    for (int ks2 = 0; ks2 < 2; ++ks2)
#pragma unroll
      for (int r = 0; r < 2; ++r) {
        int row = m0 + w * 32 + r * 16 + mr;
        if (kc < 2) {
          union { uint4 v; bfrag f; } u;
          u.v = make_uint4(0u, 0u, 0u, 0u);
          if (row < M)
            u.v = *reinterpret_cast<const uint4*>(
                &Ob[(size_t)row * 128 + kc * 64 + ks2 * 32 + quad * 8]);
          af[ks2][r] = u.f;
        } else {
          union { unsigned short s[8]; bfrag f; } u;
          if (row < M) {
            const float4* p = reinterpret_cast<const float4*>(
                &x[(size_t)row * 128 + (kc - 2) * 64 + ks2 * 32 + quad * 8]);
            float4 v0 = p[0], v1 = p[1];
            u.s[0] = f2bf(v0.x); u.s[1] = f2bf(v0.y); u.s[2] = f2bf(v0.z); u.s[3] = f2bf(v0.w);
            u.s[4] = f2bf(v1.x); u.s[5] = f2bf(v1.y); u.s[6] = f2bf(v1.z); u.s[7] = f2bf(v1.w);
          } else {
#pragma unroll
            for (int i = 0; i < 8; ++i) u.s[i] = 0;
          }
          af[ks2][r] = u.f;
        }
      }
#pragma unroll
    for (int ks2 = 0; ks2 < 2; ++ks2)
#pragma unroll
      for (int c = 0; c < 8; ++c) {
        union { uint4 v; bfrag f; } u;
        u.v = *reinterpret_cast<const uint4*>(
            &W2F[(((c * 4 + kc) * 2 + ks2) << 9) + lane * 8]);
        acc[0][c] = __builtin_amdgcn_mfma_f32_16x16x32_bf16(af[ks2][0], u.f, acc[0][c], 0, 0, 0);
        acc[1][c] = __builtin_amdgcn_mfma_f32_16x16x32_bf16(af[ks2][1], u.f, acc[1][c], 0, 0, 0);
      }
  }
  // wave-private epilogue: 4 passes of 32 fp32 cols
#pragma unroll
  for (int p = 0; p < 4; ++p) {
#pragma unroll
    for (int cc = 0; cc < 2; ++cc) {
      int c = p * 2 + cc;
      float cv = cvec[c * 16 + mr];
#pragma unroll
      for (int r = 0; r < 2; ++r)
#pragma unroll
        for (int g = 0; g < 4; ++g)
          sfw[(r * 16 + quad * 4 + g) * 36 + cc * 16 + mr] = acc[r][c][g] + cv;
    }
#pragma unroll
    for (int i = 0; i < 4; ++i) {
      int ch = i * 64 + lane;  // 256 chunks: 32 rows x 8 float4
      int row = ch >> 3, c4 = ch & 7;
      int grow = m0 + w * 32 + row;
      if (grow < M) {
        float4 v = *reinterpret_cast<const float4*>(&sfw[row * 36 + c4 * 4]);
        *reinterpret_cast<float4*>(&out[(size_t)grow * 128 + p * 32 + c4 * 4]) = v;
      }
    }
  }
}

extern "C" void kernel_launch(void* const* d_in, const int* in_sizes, int n_in,
                              void* d_out, int out_size, void* d_ws, size_t ws_size,
                              hipStream_t stream) {
  const float* x          = (const float*)d_in[0];
  const int*   fn         = (const int*)d_in[1];
  const float* in_proj_w  = (const float*)d_in[4];
  const float* in_proj_b  = (const float*)d_in[5];
  const float* out_proj_w = (const float*)d_in[6];
  const float* out_proj_b = (const float*)d_in[7];
  const float* conv_w     = (const float*)d_in[8];
  const float* conv_b     = (const float*)d_in[9];
  const int M = in_sizes[0] / 128;
  const int mt = (M + 127) / 128;
  char* ws = (char*)d_ws;

  const size_t qbytes  = (size_t)M * 128 * 2;           // Qb
  const size_t kvbytes = (size_t)M * 256 * 2;           // KVb
  const size_t wbytes  = (size_t)(384 * 128 + 128 * 256) * 2 + 512;  // WcatF+W2F+cvec

  if (ws_size >= qbytes + kvbytes + wbytes) {
    // FUSED path: KVb moves to ws (d_out is written concurrently with gathers).
    unsigned short* Qb    = (unsigned short*)ws;
    unsigned short* KVb   = (unsigned short*)(ws + qbytes);
    unsigned short* WcatF = (unsigned short*)(ws + qbytes + kvbytes);
    unsigned short* W2F   = WcatF + 384 * 128;
    float*          cvec  = (float*)(W2F + 128 * 256);

    k_prep<<<dim3(512), dim3(128), 0, stream>>>(in_proj_w, conv_w, out_proj_w,
                                                out_proj_b, conv_b, WcatF, W2F, cvec);
    k_gemm_qkv<<<dim3(mt), dim3(256), 0, stream>>>(x, WcatF, in_proj_b, Qb, KVb, M);
    k_fused<<<dim3(mt), dim3(256), 0, stream>>>(Qb, KVb, fn, x, W2F, cvec,
                                                (float*)d_out, M);
  } else {
    // LEGACY path (identical to previous best): KVb aliases d_out.
    unsigned short* KVb   = (unsigned short*)d_out;
    unsigned short* Qb    = (unsigned short*)ws;
    unsigned short* Ob    = (unsigned short*)(ws + (size_t)M * 128 * 2);
    unsigned short* WcatF = (unsigned short*)(ws + (size_t)M * 128 * 4);
    unsigned short* W2F   = WcatF + 384 * 128;
    float*          cvec  = (float*)(W2F + 128 * 256);

    k_prep<<<dim3(512), dim3(128), 0, stream>>>(in_proj_w, conv_w, out_proj_w,
                                                out_proj_b, conv_b, WcatF, W2F, cvec);
    k_gemm_qkv<<<dim3(mt), dim3(256), 0, stream>>>(x, WcatF, in_proj_b, Qb, KVb, M);
    k_attn<<<dim3((M + 3) / 4), dim3(256), 0, stream>>>(Qb, KVb, fn, Ob, M);
    k_gemm_out<<<dim3(mt), dim3(256), 0, stream>>>(Ob, x, W2F, cvec, (float*)d_out, M);
  }
}

// Round 3
// 434.831 us; speedup vs baseline: 1.0306x; 1.0306x over previous
//
#include <hip/hip_runtime.h>

typedef __bf16 bfrag __attribute__((ext_vector_type(8)));
typedef float f32x4 __attribute__((ext_vector_type(4)));

__device__ __forceinline__ unsigned short f2bf(float f) {
  unsigned u = __float_as_uint(f);
  u = (u + 0x7fffu + ((u >> 16) & 1u)) >> 16;
  return (unsigned short)u;
}
__device__ __forceinline__ float bflo(unsigned u) { return __uint_as_float(u << 16); }
__device__ __forceinline__ float bfhi(unsigned u) { return __uint_as_float(u & 0xffff0000u); }

// ---------------- weight prep: FRAGMENT-MAJOR layouts ----------------
// WcatF[((cb*8 + cB)*4 + ks)*512 + lane*8 + j]: B-frag for in_proj block cb,
//   col-block cB, k-step ks; lane=(quad*16+mr) holds row cB*16+mr, k=ks*32+quad*8+j.
// W2F[((cB*4 + kc)*2 + ks2)*512 + lane*8 + j]: same for [W2 | W00] (K=256).
// cvec = conv_b + conv_w01 @ out_proj_b
// REWRITTEN (R3): the 128x128 matmul (W2 = conv_w01 @ out_proj_w) previously ran
// as a serial 128-FMA dependent chain per thread (~117 us measured by dispatch
// algebra). Now: conv_w row staged in LDS, 8 independent accumulators, fully
// unrolled coalesced out_proj_w loads; cvec via parallel shuffle reduction.
__global__ void k_prep(const float* __restrict__ in_proj_w,
                       const float* __restrict__ conv_w,
                       const float* __restrict__ out_proj_w,
                       const float* __restrict__ out_proj_b,
                       const float* __restrict__ conv_b,
                       unsigned short* __restrict__ WcatF,
                       unsigned short* __restrict__ W2F,
                       float* __restrict__ cvec) {
  int b = blockIdx.x, t = threadIdx.x;
  if (b < 384) {
    unsigned short v = f2bf(in_proj_w[b * 128 + t]);
    int cb = b >> 7, r7 = b & 127;
    int cB = r7 >> 4, mr = r7 & 15;
    int ks = t >> 5, quad = (t >> 3) & 3, j = t & 7;
    WcatF[(((cb * 8 + cB) * 4 + ks) << 9) + (quad * 16 + mr) * 8 + j] = v;
    return;
  }
  const int c = b - 384;  // output channel (B-row), 128 blocks x 128 threads
  const int cB = c >> 4, mr = c & 15;
  __shared__ float cw[128];
  __shared__ float red[2];
  cw[t] = conv_w[(c * 128 + t) * 2 + 1];  // conv_w01 row c
  __syncthreads();

  // s = sum_k cw[k] * out_proj_w[k*128 + t]; 8 independent accumulators,
  // fully unrolled -> deep load pipeline, coalesced across t.
  float a[8] = {0.f, 0.f, 0.f, 0.f, 0.f, 0.f, 0.f, 0.f};
#pragma unroll
  for (int kk = 0; kk < 16; ++kk)
#pragma unroll
    for (int u = 0; u < 8; ++u)
      a[u] += cw[kk * 8 + u] * out_proj_w[(kk * 8 + u) * 128 + t];
  float s = ((a[0] + a[1]) + (a[2] + a[3])) + ((a[4] + a[5]) + (a[6] + a[7]));

  {  // K = t (W2 part)
    int kc = t >> 6, ks2 = (t >> 5) & 1, quad = (t >> 3) & 3, j = t & 7;
    W2F[(((cB * 4 + kc) * 2 + ks2) << 9) + (quad * 16 + mr) * 8 + j] = f2bf(s);
  }
  {  // K = 128 + t (W00 part)
    int K = 128 + t;
    int kc = K >> 6, ks2 = (K >> 5) & 1, quad = (K >> 3) & 3, j = K & 7;
    W2F[(((cB * 4 + kc) * 2 + ks2) << 9) + (quad * 16 + mr) * 8 + j] =
        f2bf(conv_w[(c * 128 + t) * 2]);
  }

  // cvec[c] = conv_b[c] + sum_k cw[k] * out_proj_b[k]  (parallel reduction)
  float p = cw[t] * out_proj_b[t];
#pragma unroll
  for (int d = 1; d < 64; d <<= 1) p += __shfl_xor(p, d);
  if ((t & 63) == 0) red[t >> 6] = p;
  __syncthreads();
  if (t == 0) cvec[c] = conv_b[c] + red[0] + red[1];
}

// ---------------- fused QKV GEMM: ZERO barriers, all frags direct ----------
// Q -> Qb (row=128 ushort). K,V -> KVb interleaved (row=256 ushort: K|V).
__global__ __launch_bounds__(256, 4) void k_gemm_qkv(
    const float* __restrict__ x, const unsigned short* __restrict__ WcatF,
    const float* __restrict__ in_proj_b, unsigned short* __restrict__ Qb,
    unsigned short* __restrict__ KVb, int M) {
  __shared__ unsigned short se[4][32 * 72];  // wave-private transpose, 18.4 KB total
  const int m0 = blockIdx.x * 128;
  const int t = threadIdx.x;
  const int w = t >> 6, lane = t & 63, quad = lane >> 4, mr = lane & 15;
  unsigned short* sew = se[w];

  // A fragments direct from x: lane (quad,mr), rows w*32+r*16+mr, k=ks*32+quad*8
  bfrag af[4][2];
#pragma unroll
  for (int ks = 0; ks < 4; ++ks)
#pragma unroll
    for (int r = 0; r < 2; ++r) {
      int row = m0 + w * 32 + r * 16 + mr;
      union { unsigned short s[8]; bfrag f; } u;
      if (row < M) {
        const float4* p =
            reinterpret_cast<const float4*>(&x[(size_t)row * 128 + ks * 32 + quad * 8]);
        float4 v0 = p[0], v1 = p[1];
        u.s[0] = f2bf(v0.x); u.s[1] = f2bf(v0.y); u.s[2] = f2bf(v0.z); u.s[3] = f2bf(v0.w);
        u.s[4] = f2bf(v1.x); u.s[5] = f2bf(v1.y); u.s[6] = f2bf(v1.z); u.s[7] = f2bf(v1.w);
      } else {
#pragma unroll
        for (int i = 0; i < 8; ++i) u.s[i] = 0;
      }
      af[ks][r] = u.f;
    }

#pragma unroll
  for (int cb = 0; cb < 3; ++cb) {
    unsigned short* dst = (cb == 0) ? Qb : KVb;
    const int ldst = (cb == 0) ? 128 : 256;
    const int cb_off = (cb == 2) ? 128 : 0;
#pragma unroll
    for (int half = 0; half < 2; ++half) {
      f32x4 acc[2][4];
#pragma unroll
      for (int r = 0; r < 2; ++r)
#pragma unroll
        for (int c = 0; c < 4; ++c) acc[r][c] = (f32x4){0.f, 0.f, 0.f, 0.f};
#pragma unroll
      for (int ks = 0; ks < 4; ++ks)
#pragma unroll
        for (int c = 0; c < 4; ++c) {
          union { uint4 v; bfrag f; } u;
          u.v = *reinterpret_cast<const uint4*>(
              &WcatF[(((cb * 8 + half * 4 + c) * 4 + ks) << 9) + lane * 8]);
          acc[0][c] = __builtin_amdgcn_mfma_f32_16x16x32_bf16(af[ks][0], u.f, acc[0][c], 0, 0, 0);
          acc[1][c] = __builtin_amdgcn_mfma_f32_16x16x32_bf16(af[ks][1], u.f, acc[1][c], 0, 0, 0);
        }
      // wave-private epilogue: 32 rows x 64 cols -> bf16 -> coalesced stores
      const float* bias = in_proj_b + cb * 128 + half * 64;
#pragma unroll
      for (int r = 0; r < 2; ++r)
#pragma unroll
        for (int c = 0; c < 4; ++c) {
          float bv = bias[c * 16 + mr];
#pragma unroll
          for (int g = 0; g < 4; ++g)
            sew[(r * 16 + quad * 4 + g) * 72 + c * 16 + mr] = f2bf(acc[r][c][g] + bv);
        }
#pragma unroll
      for (int i = 0; i < 4; ++i) {
        int ch = i * 64 + lane;  // 256 chunks: 32 rows x 8 x 16B
        int row = ch >> 3, cp = ch & 7;
        int grow = m0 + w * 32 + row;
        if (grow < M) {
          uint4 v = *reinterpret_cast<const uint4*>(&sew[row * 72 + cp * 8]);
          *reinterpret_cast<uint4*>(
              &dst[(size_t)grow * ldst + cb_off + half * 64 + cp * 8]) = v;
        }
      }
    }
  }
}

// ---------------- attention: 1 wave per row, interleaved KV gather ----------
__global__ __launch_bounds__(256) void k_attn(
    const unsigned short* __restrict__ Qb, const unsigned short* __restrict__ KVb,
    const int* __restrict__ fn, unsigned short* __restrict__ Ob, int M) {
  int w = threadIdx.x >> 6, lane = threadIdx.x & 63;
  int n = blockIdx.x * 4 + w;
  if (n >= M) return;
  const float scale = 0.17677669529663687f;  // 1/sqrt(32)
  const int l5 = lane & 31;
  uint2 qp = *reinterpret_cast<const uint2*>(&Qb[(size_t)n * 128 + 4 * l5]);
  float q0 = bflo(qp.x), q1 = bfhi(qp.x), q2 = bflo(qp.y), q3 = bfhi(qp.y);
  int idx[8];
#pragma unroll
  for (int j = 0; j < 8; ++j) idx[j] = fn[n * 9 + 1 + j];
  float o0 = 0.f, o1 = 0.f, o2 = 0.f, o3 = 0.f, sum = 0.f;
#pragma unroll
  for (int j = 0; j < 8; ++j) {
    bool valid = idx[j] < M;
    int id = valid ? idx[j] : 0;
    uint2 kv = *reinterpret_cast<const uint2*>(&KVb[(size_t)id * 256 + 4 * lane]);
    float a0 = bflo(kv.x), a1 = bfhi(kv.x), a2 = bflo(kv.y), a3 = bfhi(kv.y);
    float p = q0 * a0 + q1 * a1 + q2 * a2 + q3 * a3;
    p += __shfl_xor(p, 1);
    p += __shfl_xor(p, 2);
    p += __shfl_xor(p, 4);              // full head dot in 8-lane groups of K half
    float pu = __shfl_xor(p, 32);       // broadcast to V half
    float sf = (lane >= 32) ? pu : p;
    float s = valid ? sf * scale : -1e30f;
    float e = __expf(s);                // |s| << 88, no max-pass needed
    sum += e;
    o0 += e * a0; o1 += e * a1; o2 += e * a2; o3 += e * a3;
  }
  float inv = 1.f / sum;
  if (lane >= 32) {
    union { unsigned short s[4]; uint2 u; } p;
    p.s[0] = f2bf(o0 * inv); p.s[1] = f2bf(o1 * inv);
    p.s[2] = f2bf(o2 * inv); p.s[3] = f2bf(o3 * inv);
    *reinterpret_cast<uint2*>(&Ob[(size_t)n * 128 + 4 * l5]) = p.u;
  }
}

// ---------------- GEMM2: out = [O | x] @ [W2 | W00]^T + cvec, ZERO barriers -
__global__ __launch_bounds__(256, 4) void k_gemm_out(
    const unsigned short* __restrict__ Ob, const float* __restrict__ x,
    const unsigned short* __restrict__ W2F, const float* __restrict__ cvec,
    float* __restrict__ out, int M) {
  __shared__ float sf[4][32 * 36];  // wave-private fp32 transpose, 18.4 KB total
  const int m0 = blockIdx.x * 128;
  const int t = threadIdx.x;
  const int w = t >> 6, lane = t & 63, quad = lane >> 4, mr = lane & 15;
  float* sfw = sf[w];

  f32x4 acc[2][8];
#pragma unroll
  for (int r = 0; r < 2; ++r)
#pragma unroll
    for (int c = 0; c < 8; ++c) acc[r][c] = (f32x4){0.f, 0.f, 0.f, 0.f};

#pragma unroll
  for (int kc = 0; kc < 4; ++kc) {
    bfrag af[2][2];  // A frags for this K-chunk, direct from global
#pragma unroll
    for (int ks2 = 0; ks2 < 2; ++ks2)
#pragma unroll
      for (int r = 0; r < 2; ++r) {
        int row = m0 + w * 32 + r * 16 + mr;
        if (kc < 2) {
          union { uint4 v; bfrag f; } u;
          u.v = make_uint4(0u, 0u, 0u, 0u);
          if (row < M)
            u.v = *reinterpret_cast<const uint4*>(
                &Ob[(size_t)row * 128 + kc * 64 + ks2 * 32 + quad * 8]);
          af[ks2][r] = u.f;
        } else {
          union { unsigned short s[8]; bfrag f; } u;
          if (row < M) {
            const float4* p = reinterpret_cast<const float4*>(
                &x[(size_t)row * 128 + (kc - 2) * 64 + ks2 * 32 + quad * 8]);
            float4 v0 = p[0], v1 = p[1];
            u.s[0] = f2bf(v0.x); u.s[1] = f2bf(v0.y); u.s[2] = f2bf(v0.z); u.s[3] = f2bf(v0.w);
            u.s[4] = f2bf(v1.x); u.s[5] = f2bf(v1.y); u.s[6] = f2bf(v1.z); u.s[7] = f2bf(v1.w);
          } else {
#pragma unroll
            for (int i = 0; i < 8; ++i) u.s[i] = 0;
          }
          af[ks2][r] = u.f;
        }
      }
#pragma unroll
    for (int ks2 = 0; ks2 < 2; ++ks2)
#pragma unroll
      for (int c = 0; c < 8; ++c) {
        union { uint4 v; bfrag f; } u;
        u.v = *reinterpret_cast<const uint4*>(
            &W2F[(((c * 4 + kc) * 2 + ks2) << 9) + lane * 8]);
        acc[0][c] = __builtin_amdgcn_mfma_f32_16x16x32_bf16(af[ks2][0], u.f, acc[0][c], 0, 0, 0);
        acc[1][c] = __builtin_amdgcn_mfma_f32_16x16x32_bf16(af[ks2][1], u.f, acc[1][c], 0, 0, 0);
      }
  }
  // wave-private epilogue: 4 passes of 32 fp32 cols
#pragma unroll
  for (int p = 0; p < 4; ++p) {
#pragma unroll
    for (int cc = 0; cc < 2; ++cc) {
      int c = p * 2 + cc;
      float cv = cvec[c * 16 + mr];
#pragma unroll
      for (int r = 0; r < 2; ++r)
#pragma unroll
        for (int g = 0; g < 4; ++g)
          sfw[(r * 16 + quad * 4 + g) * 36 + cc * 16 + mr] = acc[r][c][g] + cv;
    }
#pragma unroll
    for (int i = 0; i < 4; ++i) {
      int ch = i * 64 + lane;  // 256 chunks: 32 rows x 8 float4
      int row = ch >> 3, c4 = ch & 7;
      int grow = m0 + w * 32 + row;
      if (grow < M) {
        float4 v = *reinterpret_cast<const float4*>(&sfw[row * 36 + c4 * 4]);
        *reinterpret_cast<float4*>(&out[(size_t)grow * 128 + p * 32 + c4 * 4]) = v;
      }
    }
  }
}

extern "C" void kernel_launch(void* const* d_in, const int* in_sizes, int n_in,
                              void* d_out, int out_size, void* d_ws, size_t ws_size,
                              hipStream_t stream) {
  const float* x          = (const float*)d_in[0];
  const int*   fn         = (const int*)d_in[1];
  const float* in_proj_w  = (const float*)d_in[4];
  const float* in_proj_b  = (const float*)d_in[5];
  const float* out_proj_w = (const float*)d_in[6];
  const float* out_proj_b = (const float*)d_in[7];
  const float* conv_w     = (const float*)d_in[8];
  const float* conv_b     = (const float*)d_in[9];
  const int M = in_sizes[0] / 128;

  // KV (bf16, interleaved, 512B/row) fills d_out exactly; dead before GEMM2 writes out.
  unsigned short* KVb = (unsigned short*)d_out;
  char* ws = (char*)d_ws;
  unsigned short* Qb    = (unsigned short*)ws;
  unsigned short* Ob    = (unsigned short*)(ws + (size_t)M * 128 * 2);
  unsigned short* WcatF = (unsigned short*)(ws + (size_t)M * 128 * 4);
  unsigned short* W2F   = WcatF + 384 * 128;
  float*          cvec  = (float*)(W2F + 128 * 256);

  const int mt = (M + 127) / 128;
  k_prep<<<dim3(512), dim3(128), 0, stream>>>(in_proj_w, conv_w, out_proj_w,
                                              out_proj_b, conv_b, WcatF, W2F, cvec);
  k_gemm_qkv<<<dim3(mt), dim3(256), 0, stream>>>(x, WcatF, in_proj_b, Qb, KVb, M);
  k_attn<<<dim3((M + 3) / 4), dim3(256), 0, stream>>>(Qb, KVb, fn, Ob, M);
  k_gemm_out<<<dim3(mt), dim3(256), 0, stream>>>(Ob, x, W2F, cvec, (float*)d_out, M);
}

// Round 4
// 433.668 us; speedup vs baseline: 1.0334x; 1.0027x over previous
//
#include <hip/hip_runtime.h>

typedef __bf16 bfrag __attribute__((ext_vector_type(8)));
typedef float f32x4 __attribute__((ext_vector_type(4)));

__device__ __forceinline__ unsigned short f2bf(float f) {
  unsigned u = __float_as_uint(f);
  u = (u + 0x7fffu + ((u >> 16) & 1u)) >> 16;
  return (unsigned short)u;
}
__device__ __forceinline__ float bflo(unsigned u) { return __uint_as_float(u << 16); }
__device__ __forceinline__ float bfhi(unsigned u) { return __uint_as_float(u & 0xffff0000u); }

// ---------------- weight prep: FRAGMENT-MAJOR layouts ----------------
// WcatF[((cb*8 + cB)*4 + ks)*512 + lane*8 + j]: B-frag for in_proj block cb,
//   col-block cB, k-step ks; lane=(quad*16+mr) holds row cB*16+mr, k=ks*32+quad*8+j.
// W2F[((cB*4 + kc)*2 + ks2)*512 + lane*8 + j]: same for [W2 | W00] (K=256).
// cvec = conv_b + conv_w01 @ out_proj_b
__global__ void k_prep(const float* __restrict__ in_proj_w,
                       const float* __restrict__ conv_w,
                       const float* __restrict__ out_proj_w,
                       const float* __restrict__ out_proj_b,
                       const float* __restrict__ conv_b,
                       unsigned short* __restrict__ WcatF,
                       unsigned short* __restrict__ W2F,
                       float* __restrict__ cvec) {
  int b = blockIdx.x, t = threadIdx.x;
  if (b < 384) {
    unsigned short v = f2bf(in_proj_w[b * 128 + t]);
    int cb = b >> 7, r7 = b & 127;
    int cB = r7 >> 4, mr = r7 & 15;
    int ks = t >> 5, quad = (t >> 3) & 3, j = t & 7;
    WcatF[(((cb * 8 + cB) * 4 + ks) << 9) + (quad * 16 + mr) * 8 + j] = v;
    return;
  }
  const int c = b - 384;  // output channel (B-row), 128 blocks x 128 threads
  const int cB = c >> 4, mr = c & 15;
  __shared__ float cw[128];
  __shared__ float red[2];
  cw[t] = conv_w[(c * 128 + t) * 2 + 1];  // conv_w01 row c
  __syncthreads();

  // s = sum_k cw[k] * out_proj_w[k*128 + t]; 8 independent accumulators,
  // fully unrolled -> deep load pipeline, coalesced across t.
  float a[8] = {0.f, 0.f, 0.f, 0.f, 0.f, 0.f, 0.f, 0.f};
#pragma unroll
  for (int kk = 0; kk < 16; ++kk)
#pragma unroll
    for (int u = 0; u < 8; ++u)
      a[u] += cw[kk * 8 + u] * out_proj_w[(kk * 8 + u) * 128 + t];
  float s = ((a[0] + a[1]) + (a[2] + a[3])) + ((a[4] + a[5]) + (a[6] + a[7]));

  {  // K = t (W2 part)
    int kc = t >> 6, ks2 = (t >> 5) & 1, quad = (t >> 3) & 3, j = t & 7;
    W2F[(((cB * 4 + kc) * 2 + ks2) << 9) + (quad * 16 + mr) * 8 + j] = f2bf(s);
  }
  {  // K = 128 + t (W00 part)
    int K = 128 + t;
    int kc = K >> 6, ks2 = (K >> 5) & 1, quad = (K >> 3) & 3, j = K & 7;
    W2F[(((cB * 4 + kc) * 2 + ks2) << 9) + (quad * 16 + mr) * 8 + j] =
        f2bf(conv_w[(c * 128 + t) * 2]);
  }

  // cvec[c] = conv_b[c] + sum_k cw[k] * out_proj_b[k]  (parallel reduction)
  float p = cw[t] * out_proj_b[t];
#pragma unroll
  for (int d = 1; d < 64; d <<= 1) p += __shfl_xor(p, d);
  if ((t & 63) == 0) red[t >> 6] = p;
  __syncthreads();
  if (t == 0) cvec[c] = conv_b[c] + red[0] + red[1];
}

// ---------------- fused QKV GEMM: ZERO barriers, all frags direct ----------
// Q -> Qb (row=128 ushort). K,V -> KVb interleaved (row=256 ushort: K|V).
__global__ __launch_bounds__(256, 4) void k_gemm_qkv(
    const float* __restrict__ x, const unsigned short* __restrict__ WcatF,
    const float* __restrict__ in_proj_b, unsigned short* __restrict__ Qb,
    unsigned short* __restrict__ KVb, int M) {
  __shared__ unsigned short se[4][32 * 72];  // wave-private transpose, 18.4 KB total
  const int m0 = blockIdx.x * 128;
  const int t = threadIdx.x;
  const int w = t >> 6, lane = t & 63, quad = lane >> 4, mr = lane & 15;
  unsigned short* sew = se[w];

  // A fragments direct from x: lane (quad,mr), rows w*32+r*16+mr, k=ks*32+quad*8
  bfrag af[4][2];
#pragma unroll
  for (int ks = 0; ks < 4; ++ks)
#pragma unroll
    for (int r = 0; r < 2; ++r) {
      int row = m0 + w * 32 + r * 16 + mr;
      union { unsigned short s[8]; bfrag f; } u;
      if (row < M) {
        const float4* p =
            reinterpret_cast<const float4*>(&x[(size_t)row * 128 + ks * 32 + quad * 8]);
        float4 v0 = p[0], v1 = p[1];
        u.s[0] = f2bf(v0.x); u.s[1] = f2bf(v0.y); u.s[2] = f2bf(v0.z); u.s[3] = f2bf(v0.w);
        u.s[4] = f2bf(v1.x); u.s[5] = f2bf(v1.y); u.s[6] = f2bf(v1.z); u.s[7] = f2bf(v1.w);
      } else {
#pragma unroll
        for (int i = 0; i < 8; ++i) u.s[i] = 0;
      }
      af[ks][r] = u.f;
    }

#pragma unroll
  for (int cb = 0; cb < 3; ++cb) {
    unsigned short* dst = (cb == 0) ? Qb : KVb;
    const int ldst = (cb == 0) ? 128 : 256;
    const int cb_off = (cb == 2) ? 128 : 0;
#pragma unroll
    for (int half = 0; half < 2; ++half) {
      f32x4 acc[2][4];
#pragma unroll
      for (int r = 0; r < 2; ++r)
#pragma unroll
        for (int c = 0; c < 4; ++c) acc[r][c] = (f32x4){0.f, 0.f, 0.f, 0.f};
#pragma unroll
      for (int ks = 0; ks < 4; ++ks)
#pragma unroll
        for (int c = 0; c < 4; ++c) {
          union { uint4 v; bfrag f; } u;
          u.v = *reinterpret_cast<const uint4*>(
              &WcatF[(((cb * 8 + half * 4 + c) * 4 + ks) << 9) + lane * 8]);
          acc[0][c] = __builtin_amdgcn_mfma_f32_16x16x32_bf16(af[ks][0], u.f, acc[0][c], 0, 0, 0);
          acc[1][c] = __builtin_amdgcn_mfma_f32_16x16x32_bf16(af[ks][1], u.f, acc[1][c], 0, 0, 0);
        }
      // wave-private epilogue: 32 rows x 64 cols -> bf16 -> coalesced stores
      const float* bias = in_proj_b + cb * 128 + half * 64;
#pragma unroll
      for (int r = 0; r < 2; ++r)
#pragma unroll
        for (int c = 0; c < 4; ++c) {
          float bv = bias[c * 16 + mr];
#pragma unroll
          for (int g = 0; g < 4; ++g)
            sew[(r * 16 + quad * 4 + g) * 72 + c * 16 + mr] = f2bf(acc[r][c][g] + bv);
        }
#pragma unroll
      for (int i = 0; i < 4; ++i) {
        int ch = i * 64 + lane;  // 256 chunks: 32 rows x 8 x 16B
        int row = ch >> 3, cp = ch & 7;
        int grow = m0 + w * 32 + row;
        if (grow < M) {
          uint4 v = *reinterpret_cast<const uint4*>(&sew[row * 72 + cp * 8]);
          *reinterpret_cast<uint4*>(
              &dst[(size_t)grow * ldst + cb_off + half * 64 + cp * 8]) = v;
        }
      }
    }
  }
}

// ---------------- attention v2: 2 rows per wave, zero wasted lanes ---------
// Each 32-lane half-wave owns one row. Lane l5 holds K cols 4*l5..+3 AND
// V cols 4*l5..+3 of the gathered neighbor row (two uint2 loads, +128 apart).
// Head dim = 32 = 8 lanes; the xor 1/2/4 tree gives the per-head score, and
// the V values in the same 8-lane group belong to the same head, so the old
// cross-half broadcast shuffle is gone. ~2x fewer VALU ops per row; reduction
// tree bitwise-identical to v1.
__global__ __launch_bounds__(256) void k_attn(
    const unsigned short* __restrict__ Qb, const unsigned short* __restrict__ KVb,
    const int* __restrict__ fn, unsigned short* __restrict__ Ob, int M) {
  const int w = threadIdx.x >> 6, lane = threadIdx.x & 63;
  const int hf = lane >> 5, l5 = lane & 31;
  const int n = blockIdx.x * 8 + w * 2 + hf;  // 8 rows per block
  if (n >= M) return;  // uniform per 32-lane half; shuffles stay in 8-groups
  const float scale = 0.17677669529663687f;  // 1/sqrt(32)
  uint2 qp = *reinterpret_cast<const uint2*>(&Qb[(size_t)n * 128 + 4 * l5]);
  float q0 = bflo(qp.x), q1 = bfhi(qp.x), q2 = bflo(qp.y), q3 = bfhi(qp.y);
  int idx[8];
#pragma unroll
  for (int j = 0; j < 8; ++j) idx[j] = fn[n * 9 + 1 + j];
  float o0 = 0.f, o1 = 0.f, o2 = 0.f, o3 = 0.f, sum = 0.f;
#pragma unroll
  for (int j = 0; j < 8; ++j) {
    bool valid = idx[j] < M;
    int id = valid ? idx[j] : 0;
    const unsigned short* rowp = &KVb[(size_t)id * 256 + 4 * l5];
    uint2 kk = *reinterpret_cast<const uint2*>(rowp);        // K cols 4*l5..+3
    uint2 vv = *reinterpret_cast<const uint2*>(rowp + 128);  // V cols 4*l5..+3
    float k0 = bflo(kk.x), k1 = bfhi(kk.x), k2 = bflo(kk.y), k3 = bfhi(kk.y);
    float p = q0 * k0 + q1 * k1 + q2 * k2 + q3 * k3;
    p += __shfl_xor(p, 1);
    p += __shfl_xor(p, 2);
    p += __shfl_xor(p, 4);  // per-head dot (8 lanes = 32 dims), same tree as v1
    float s = valid ? p * scale : -1e30f;
    float e = __expf(s);    // |s| << 88, no max-pass needed
    sum += e;
    float v0 = bflo(vv.x), v1 = bfhi(vv.x), v2 = bflo(vv.y), v3 = bfhi(vv.y);
    o0 += e * v0; o1 += e * v1; o2 += e * v2; o3 += e * v3;
  }
  float inv = 1.f / sum;
  union { unsigned short s[4]; uint2 u; } pk;
  pk.s[0] = f2bf(o0 * inv); pk.s[1] = f2bf(o1 * inv);
  pk.s[2] = f2bf(o2 * inv); pk.s[3] = f2bf(o3 * inv);
  *reinterpret_cast<uint2*>(&Ob[(size_t)n * 128 + 4 * l5]) = pk.u;
}

// ---------------- GEMM2: out = [O | x] @ [W2 | W00]^T + cvec, ZERO barriers -
__global__ __launch_bounds__(256, 4) void k_gemm_out(
    const unsigned short* __restrict__ Ob, const float* __restrict__ x,
    const unsigned short* __restrict__ W2F, const float* __restrict__ cvec,
    float* __restrict__ out, int M) {
  __shared__ float sf[4][32 * 36];  // wave-private fp32 transpose, 18.4 KB total
  const int m0 = blockIdx.x * 128;
  const int t = threadIdx.x;
  const int w = t >> 6, lane = t & 63, quad = lane >> 4, mr = lane & 15;
  float* sfw = sf[w];

  f32x4 acc[2][8];
#pragma unroll
  for (int r = 0; r < 2; ++r)
#pragma unroll
    for (int c = 0; c < 8; ++c) acc[r][c] = (f32x4){0.f, 0.f, 0.f, 0.f};

#pragma unroll
  for (int kc = 0; kc < 4; ++kc) {
    bfrag af[2][2];  // A frags for this K-chunk, direct from global
#pragma unroll
    for (int ks2 = 0; ks2 < 2; ++ks2)
#pragma unroll
      for (int r = 0; r < 2; ++r) {
        int row = m0 + w * 32 + r * 16 + mr;
        if (kc < 2) {
          union { uint4 v; bfrag f; } u;
          u.v = make_uint4(0u, 0u, 0u, 0u);
          if (row < M)
            u.v = *reinterpret_cast<const uint4*>(
                &Ob[(size_t)row * 128 + kc * 64 + ks2 * 32 + quad * 8]);
          af[ks2][r] = u.f;
        } else {
          union { unsigned short s[8]; bfrag f; } u;
          if (row < M) {
            const float4* p = reinterpret_cast<const float4*>(
                &x[(size_t)row * 128 + (kc - 2) * 64 + ks2 * 32 + quad * 8]);
            float4 v0 = p[0], v1 = p[1];
            u.s[0] = f2bf(v0.x); u.s[1] = f2bf(v0.y); u.s[2] = f2bf(v0.z); u.s[3] = f2bf(v0.w);
            u.s[4] = f2bf(v1.x); u.s[5] = f2bf(v1.y); u.s[6] = f2bf(v1.z); u.s[7] = f2bf(v1.w);
          } else {
#pragma unroll
            for (int i = 0; i < 8; ++i) u.s[i] = 0;
          }
          af[ks2][r] = u.f;
        }
      }
#pragma unroll
    for (int ks2 = 0; ks2 < 2; ++ks2)
#pragma unroll
      for (int c = 0; c < 8; ++c) {
        union { uint4 v; bfrag f; } u;
        u.v = *reinterpret_cast<const uint4*>(
            &W2F[(((c * 4 + kc) * 2 + ks2) << 9) + lane * 8]);
        acc[0][c] = __builtin_amdgcn_mfma_f32_16x16x32_bf16(af[ks2][0], u.f, acc[0][c], 0, 0, 0);
        acc[1][c] = __builtin_amdgcn_mfma_f32_16x16x32_bf16(af[ks2][1], u.f, acc[1][c], 0, 0, 0);
      }
  }
  // wave-private epilogue: 4 passes of 32 fp32 cols
#pragma unroll
  for (int p = 0; p < 4; ++p) {
#pragma unroll
    for (int cc = 0; cc < 2; ++cc) {
      int c = p * 2 + cc;
      float cv = cvec[c * 16 + mr];
#pragma unroll
      for (int r = 0; r < 2; ++r)
#pragma unroll
        for (int g = 0; g < 4; ++g)
          sfw[(r * 16 + quad * 4 + g) * 36 + cc * 16 + mr] = acc[r][c][g] + cv;
    }
#pragma unroll
    for (int i = 0; i < 4; ++i) {
      int ch = i * 64 + lane;  // 256 chunks: 32 rows x 8 float4
      int row = ch >> 3, c4 = ch & 7;
      int grow = m0 + w * 32 + row;
      if (grow < M) {
        float4 v = *reinterpret_cast<const float4*>(&sfw[row * 36 + c4 * 4]);
        *reinterpret_cast<float4*>(&out[(size_t)grow * 128 + p * 32 + c4 * 4]) = v;
      }
    }
  }
}

extern "C" void kernel_launch(void* const* d_in, const int* in_sizes, int n_in,
                              void* d_out, int out_size, void* d_ws, size_t ws_size,
                              hipStream_t stream) {
  const float* x          = (const float*)d_in[0];
  const int*   fn         = (const int*)d_in[1];
  const float* in_proj_w  = (const float*)d_in[4];
  const float* in_proj_b  = (const float*)d_in[5];
  const float* out_proj_w = (const float*)d_in[6];
  const float* out_proj_b = (const float*)d_in[7];
  const float* conv_w     = (const float*)d_in[8];
  const float* conv_b     = (const float*)d_in[9];
  const int M = in_sizes[0] / 128;

  // KV (bf16, interleaved, 512B/row) fills d_out exactly; dead before GEMM2 writes out.
  unsigned short* KVb = (unsigned short*)d_out;
  char* ws = (char*)d_ws;
  unsigned short* Qb    = (unsigned short*)ws;
  unsigned short* Ob    = (unsigned short*)(ws + (size_t)M * 128 * 2);
  unsigned short* WcatF = (unsigned short*)(ws + (size_t)M * 128 * 4);
  unsigned short* W2F   = WcatF + 384 * 128;
  float*          cvec  = (float*)(W2F + 128 * 256);

  const int mt = (M + 127) / 128;
  k_prep<<<dim3(512), dim3(128), 0, stream>>>(in_proj_w, conv_w, out_proj_w,
                                              out_proj_b, conv_b, WcatF, W2F, cvec);
  k_gemm_qkv<<<dim3(mt), dim3(256), 0, stream>>>(x, WcatF, in_proj_b, Qb, KVb, M);
  k_attn<<<dim3((M + 7) / 8), dim3(256), 0, stream>>>(Qb, KVb, fn, Ob, M);
  k_gemm_out<<<dim3(mt), dim3(256), 0, stream>>>(Ob, x, W2F, cvec, (float*)d_out, M);
}

// Round 5
// 431.062 us; speedup vs baseline: 1.0396x; 1.0060x over previous
//
#include <hip/hip_runtime.h>

typedef __bf16 bfrag __attribute__((ext_vector_type(8)));
typedef float f32x4 __attribute__((ext_vector_type(4)));

__device__ __forceinline__ unsigned short f2bf(float f) {
  unsigned u = __float_as_uint(f);
  u = (u + 0x7fffu + ((u >> 16) & 1u)) >> 16;
  return (unsigned short)u;
}
__device__ __forceinline__ float bflo(unsigned u) { return __uint_as_float(u << 16); }
__device__ __forceinline__ float bfhi(unsigned u) { return __uint_as_float(u & 0xffff0000u); }

// ---------------- weight prep: FRAGMENT-MAJOR layouts ----------------
// WcatF[((cb*8 + cB)*4 + ks)*512 + lane*8 + j]: B-frag for in_proj block cb,
//   col-block cB, k-step ks; lane=(quad*16+mr) holds row cB*16+mr, k=ks*32+quad*8+j.
// W2F[((cB*4 + kc)*2 + ks2)*512 + lane*8 + j]: same for [W2 | W00] (K=256).
// cvec = conv_b + conv_w01 @ out_proj_b
__global__ void k_prep(const float* __restrict__ in_proj_w,
                       const float* __restrict__ conv_w,
                       const float* __restrict__ out_proj_w,
                       const float* __restrict__ out_proj_b,
                       const float* __restrict__ conv_b,
                       unsigned short* __restrict__ WcatF,
                       unsigned short* __restrict__ W2F,
                       float* __restrict__ cvec) {
  int b = blockIdx.x, t = threadIdx.x;
  if (b < 384) {
    unsigned short v = f2bf(in_proj_w[b * 128 + t]);
    int cb = b >> 7, r7 = b & 127;
    int cB = r7 >> 4, mr = r7 & 15;
    int ks = t >> 5, quad = (t >> 3) & 3, j = t & 7;
    WcatF[(((cb * 8 + cB) * 4 + ks) << 9) + (quad * 16 + mr) * 8 + j] = v;
    return;
  }
  const int c = b - 384;  // output channel (B-row), 128 blocks x 128 threads
  const int cB = c >> 4, mr = c & 15;
  __shared__ float cw[128];
  __shared__ float red[2];
  cw[t] = conv_w[(c * 128 + t) * 2 + 1];  // conv_w01 row c
  __syncthreads();

  // s = sum_k cw[k] * out_proj_w[k*128 + t]; 8 independent accumulators,
  // fully unrolled -> deep load pipeline, coalesced across t.
  float a[8] = {0.f, 0.f, 0.f, 0.f, 0.f, 0.f, 0.f, 0.f};
#pragma unroll
  for (int kk = 0; kk < 16; ++kk)
#pragma unroll
    for (int u = 0; u < 8; ++u)
      a[u] += cw[kk * 8 + u] * out_proj_w[(kk * 8 + u) * 128 + t];
  float s = ((a[0] + a[1]) + (a[2] + a[3])) + ((a[4] + a[5]) + (a[6] + a[7]));

  {  // K = t (W2 part)
    int kc = t >> 6, ks2 = (t >> 5) & 1, quad = (t >> 3) & 3, j = t & 7;
    W2F[(((cB * 4 + kc) * 2 + ks2) << 9) + (quad * 16 + mr) * 8 + j] = f2bf(s);
  }
  {  // K = 128 + t (W00 part)
    int K = 128 + t;
    int kc = K >> 6, ks2 = (K >> 5) & 1, quad = (K >> 3) & 3, j = K & 7;
    W2F[(((cB * 4 + kc) * 2 + ks2) << 9) + (quad * 16 + mr) * 8 + j] =
        f2bf(conv_w[(c * 128 + t) * 2]);
  }

  // cvec[c] = conv_b[c] + sum_k cw[k] * out_proj_b[k]  (parallel reduction)
  float p = cw[t] * out_proj_b[t];
#pragma unroll
  for (int d = 1; d < 64; d <<= 1) p += __shfl_xor(p, d);
  if ((t & 63) == 0) red[t >> 6] = p;
  __syncthreads();
  if (t == 0) cvec[c] = conv_b[c] + red[0] + red[1];
}

// ---------------- fused QKV GEMM: ZERO barriers, all frags direct ----------
// Q -> Qb (row=128 ushort). K,V -> KVb interleaved (row=256 ushort: K|V).
__global__ __launch_bounds__(256, 4) void k_gemm_qkv(
    const float* __restrict__ x, const unsigned short* __restrict__ WcatF,
    const float* __restrict__ in_proj_b, unsigned short* __restrict__ Qb,
    unsigned short* __restrict__ KVb, int M) {
  __shared__ unsigned short se[4][32 * 72];  // wave-private transpose, 18.4 KB total
  const int m0 = blockIdx.x * 128;
  const int t = threadIdx.x;
  const int w = t >> 6, lane = t & 63, quad = lane >> 4, mr = lane & 15;
  unsigned short* sew = se[w];

  // A fragments direct from x: lane (quad,mr), rows w*32+r*16+mr, k=ks*32+quad*8
  bfrag af[4][2];
#pragma unroll
  for (int ks = 0; ks < 4; ++ks)
#pragma unroll
    for (int r = 0; r < 2; ++r) {
      int row = m0 + w * 32 + r * 16 + mr;
      union { unsigned short s[8]; bfrag f; } u;
      if (row < M) {
        const float4* p =
            reinterpret_cast<const float4*>(&x[(size_t)row * 128 + ks * 32 + quad * 8]);
        float4 v0 = p[0], v1 = p[1];
        u.s[0] = f2bf(v0.x); u.s[1] = f2bf(v0.y); u.s[2] = f2bf(v0.z); u.s[3] = f2bf(v0.w);
        u.s[4] = f2bf(v1.x); u.s[5] = f2bf(v1.y); u.s[6] = f2bf(v1.z); u.s[7] = f2bf(v1.w);
      } else {
#pragma unroll
        for (int i = 0; i < 8; ++i) u.s[i] = 0;
      }
      af[ks][r] = u.f;
    }

#pragma unroll
  for (int cb = 0; cb < 3; ++cb) {
    unsigned short* dst = (cb == 0) ? Qb : KVb;
    const int ldst = (cb == 0) ? 128 : 256;
    const int cb_off = (cb == 2) ? 128 : 0;
#pragma unroll
    for (int half = 0; half < 2; ++half) {
      f32x4 acc[2][4];
#pragma unroll
      for (int r = 0; r < 2; ++r)
#pragma unroll
        for (int c = 0; c < 4; ++c) acc[r][c] = (f32x4){0.f, 0.f, 0.f, 0.f};
#pragma unroll
      for (int ks = 0; ks < 4; ++ks)
#pragma unroll
        for (int c = 0; c < 4; ++c) {
          union { uint4 v; bfrag f; } u;
          u.v = *reinterpret_cast<const uint4*>(
              &WcatF[(((cb * 8 + half * 4 + c) * 4 + ks) << 9) + lane * 8]);
          acc[0][c] = __builtin_amdgcn_mfma_f32_16x16x32_bf16(af[ks][0], u.f, acc[0][c], 0, 0, 0);
          acc[1][c] = __builtin_amdgcn_mfma_f32_16x16x32_bf16(af[ks][1], u.f, acc[1][c], 0, 0, 0);
        }
      // wave-private epilogue: 32 rows x 64 cols -> bf16 -> coalesced stores
      const float* bias = in_proj_b + cb * 128 + half * 64;
#pragma unroll
      for (int r = 0; r < 2; ++r)
#pragma unroll
        for (int c = 0; c < 4; ++c) {
          float bv = bias[c * 16 + mr];
#pragma unroll
          for (int g = 0; g < 4; ++g)
            sew[(r * 16 + quad * 4 + g) * 72 + c * 16 + mr] = f2bf(acc[r][c][g] + bv);
        }
#pragma unroll
      for (int i = 0; i < 4; ++i) {
        int ch = i * 64 + lane;  // 256 chunks: 32 rows x 8 x 16B
        int row = ch >> 3, cp = ch & 7;
        int grow = m0 + w * 32 + row;
        if (grow < M) {
          uint4 v = *reinterpret_cast<const uint4*>(&sew[row * 72 + cp * 8]);
          *reinterpret_cast<uint4*>(
              &dst[(size_t)grow * ldst + cb_off + half * 64 + cp * 8]) = v;
        }
      }
    }
  }
}

// ---------------- attention v3: 2 rows/wave + all 16 gathers in flight -----
// v2 post-mortem: halving VALU left dur at 119 us -> memory-side bound.
// VGPR=36 proved only ~2 gather loads in flight (16 outstanding uint2 need
// 32 VGPR). v3: issue ALL K/V loads before any compute (deep MLP), and use
// nontemporal loads for single-use streams (Qb, fn) so they don't evict the
// x8-reused KVb from L2/L3. KVb gathers stay cached. Math bitwise-identical.
__global__ __launch_bounds__(256) void k_attn(
    const unsigned short* __restrict__ Qb, const unsigned short* __restrict__ KVb,
    const int* __restrict__ fn, unsigned short* __restrict__ Ob, int M) {
  const int w = threadIdx.x >> 6, lane = threadIdx.x & 63;
  const int hf = lane >> 5, l5 = lane & 31;
  const int n = blockIdx.x * 8 + w * 2 + hf;  // 8 rows per block
  if (n >= M) return;  // uniform per 32-lane half; shuffles stay in 8-groups
  const float scale = 0.17677669529663687f;  // 1/sqrt(32)

  // Q: single-use stream -> nontemporal (no cache allocate)
  unsigned long long q8 = __builtin_nontemporal_load(
      reinterpret_cast<const unsigned long long*>(&Qb[(size_t)n * 128 + 4 * l5]));
  float q0 = bflo((unsigned)q8), q1 = bfhi((unsigned)q8);
  float q2 = bflo((unsigned)(q8 >> 32)), q3 = bfhi((unsigned)(q8 >> 32));

  int idx[8];
#pragma unroll
  for (int j = 0; j < 8; ++j) idx[j] = __builtin_nontemporal_load(&fn[n * 9 + 1 + j]);

  // Issue ALL 16 gather loads up-front: 16 outstanding loads per half-wave.
  uint2 kk[8], vv[8];
#pragma unroll
  for (int j = 0; j < 8; ++j) {
    int id = (idx[j] < M) ? idx[j] : 0;
    const unsigned short* rowp = &KVb[(size_t)id * 256 + 4 * l5];
    kk[j] = *reinterpret_cast<const uint2*>(rowp);        // K cols 4*l5..+3
    vv[j] = *reinterpret_cast<const uint2*>(rowp + 128);  // V cols 4*l5..+3
  }

  float o0 = 0.f, o1 = 0.f, o2 = 0.f, o3 = 0.f, sum = 0.f;
#pragma unroll
  for (int j = 0; j < 8; ++j) {
    float k0 = bflo(kk[j].x), k1 = bfhi(kk[j].x), k2 = bflo(kk[j].y), k3 = bfhi(kk[j].y);
    float p = q0 * k0 + q1 * k1 + q2 * k2 + q3 * k3;
    p += __shfl_xor(p, 1);
    p += __shfl_xor(p, 2);
    p += __shfl_xor(p, 4);  // per-head dot (8 lanes = 32 dims), same tree as v2
    float s = (idx[j] < M) ? p * scale : -1e30f;
    float e = __expf(s);    // |s| << 88, no max-pass needed
    sum += e;
    float v0 = bflo(vv[j].x), v1 = bfhi(vv[j].x), v2 = bflo(vv[j].y), v3 = bfhi(vv[j].y);
    o0 += e * v0; o1 += e * v1; o2 += e * v2; o3 += e * v3;
  }
  float inv = 1.f / sum;
  union { unsigned short s[4]; uint2 u; } pk;
  pk.s[0] = f2bf(o0 * inv); pk.s[1] = f2bf(o1 * inv);
  pk.s[2] = f2bf(o2 * inv); pk.s[3] = f2bf(o3 * inv);
  *reinterpret_cast<uint2*>(&Ob[(size_t)n * 128 + 4 * l5]) = pk.u;
}

// ---------------- GEMM2: out = [O | x] @ [W2 | W00]^T + cvec, ZERO barriers -
__global__ __launch_bounds__(256, 4) void k_gemm_out(
    const unsigned short* __restrict__ Ob, const float* __restrict__ x,
    const unsigned short* __restrict__ W2F, const float* __restrict__ cvec,
    float* __restrict__ out, int M) {
  __shared__ float sf[4][32 * 36];  // wave-private fp32 transpose, 18.4 KB total
  const int m0 = blockIdx.x * 128;
  const int t = threadIdx.x;
  const int w = t >> 6, lane = t & 63, quad = lane >> 4, mr = lane & 15;
  float* sfw = sf[w];

  f32x4 acc[2][8];
#pragma unroll
  for (int r = 0; r < 2; ++r)
#pragma unroll
    for (int c = 0; c < 8; ++c) acc[r][c] = (f32x4){0.f, 0.f, 0.f, 0.f};

#pragma unroll
  for (int kc = 0; kc < 4; ++kc) {
    bfrag af[2][2];  // A frags for this K-chunk, direct from global
#pragma unroll
    for (int ks2 = 0; ks2 < 2; ++ks2)
#pragma unroll
      for (int r = 0; r < 2; ++r) {
        int row = m0 + w * 32 + r * 16 + mr;
        if (kc < 2) {
          union { uint4 v; bfrag f; } u;
          u.v = make_uint4(0u, 0u, 0u, 0u);
          if (row < M)
            u.v = *reinterpret_cast<const uint4*>(
                &Ob[(size_t)row * 128 + kc * 64 + ks2 * 32 + quad * 8]);
          af[ks2][r] = u.f;
        } else {
          union { unsigned short s[8]; bfrag f; } u;
          if (row < M) {
            const float4* p = reinterpret_cast<const float4*>(
                &x[(size_t)row * 128 + (kc - 2) * 64 + ks2 * 32 + quad * 8]);
            float4 v0 = p[0], v1 = p[1];
            u.s[0] = f2bf(v0.x); u.s[1] = f2bf(v0.y); u.s[2] = f2bf(v0.z); u.s[3] = f2bf(v0.w);
            u.s[4] = f2bf(v1.x); u.s[5] = f2bf(v1.y); u.s[6] = f2bf(v1.z); u.s[7] = f2bf(v1.w);
          } else {
#pragma unroll
            for (int i = 0; i < 8; ++i) u.s[i] = 0;
          }
          af[ks2][r] = u.f;
        }
      }
#pragma unroll
    for (int ks2 = 0; ks2 < 2; ++ks2)
#pragma unroll
      for (int c = 0; c < 8; ++c) {
        union { uint4 v; bfrag f; } u;
        u.v = *reinterpret_cast<const uint4*>(
            &W2F[(((c * 4 + kc) * 2 + ks2) << 9) + lane * 8]);
        acc[0][c] = __builtin_amdgcn_mfma_f32_16x16x32_bf16(af[ks2][0], u.f, acc[0][c], 0, 0, 0);
        acc[1][c] = __builtin_amdgcn_mfma_f32_16x16x32_bf16(af[ks2][1], u.f, acc[1][c], 0, 0, 0);
      }
  }
  // wave-private epilogue: 4 passes of 32 fp32 cols
#pragma unroll
  for (int p = 0; p < 4; ++p) {
#pragma unroll
    for (int cc = 0; cc < 2; ++cc) {
      int c = p * 2 + cc;
      float cv = cvec[c * 16 + mr];
#pragma unroll
      for (int r = 0; r < 2; ++r)
#pragma unroll
        for (int g = 0; g < 4; ++g)
          sfw[(r * 16 + quad * 4 + g) * 36 + cc * 16 + mr] = acc[r][c][g] + cv;
    }
#pragma unroll
    for (int i = 0; i < 4; ++i) {
      int ch = i * 64 + lane;  // 256 chunks: 32 rows x 8 float4
      int row = ch >> 3, c4 = ch & 7;
      int grow = m0 + w * 32 + row;
      if (grow < M) {
        float4 v = *reinterpret_cast<const float4*>(&sfw[row * 36 + c4 * 4]);
        *reinterpret_cast<float4*>(&out[(size_t)grow * 128 + p * 32 + c4 * 4]) = v;
      }
    }
  }
}

extern "C" void kernel_launch(void* const* d_in, const int* in_sizes, int n_in,
                              void* d_out, int out_size, void* d_ws, size_t ws_size,
                              hipStream_t stream) {
  const float* x          = (const float*)d_in[0];
  const int*   fn         = (const int*)d_in[1];
  const float* in_proj_w  = (const float*)d_in[4];
  const float* in_proj_b  = (const float*)d_in[5];
  const float* out_proj_w = (const float*)d_in[6];
  const float* out_proj_b = (const float*)d_in[7];
  const float* conv_w     = (const float*)d_in[8];
  const float* conv_b     = (const float*)d_in[9];
  const int M = in_sizes[0] / 128;

  // KV (bf16, interleaved, 512B/row) fills d_out exactly; dead before GEMM2 writes out.
  unsigned short* KVb = (unsigned short*)d_out;
  char* ws = (char*)d_ws;
  unsigned short* Qb    = (unsigned short*)ws;
  unsigned short* Ob    = (unsigned short*)(ws + (size_t)M * 128 * 2);
  unsigned short* WcatF = (unsigned short*)(ws + (size_t)M * 128 * 4);
  unsigned short* W2F   = WcatF + 384 * 128;
  float*          cvec  = (float*)(W2F + 128 * 256);

  const int mt = (M + 127) / 128;
  k_prep<<<dim3(512), dim3(128), 0, stream>>>(in_proj_w, conv_w, out_proj_w,
                                              out_proj_b, conv_b, WcatF, W2F, cvec);
  k_gemm_qkv<<<dim3(mt), dim3(256), 0, stream>>>(x, WcatF, in_proj_b, Qb, KVb, M);
  k_attn<<<dim3((M + 7) / 8), dim3(256), 0, stream>>>(Qb, KVb, fn, Ob, M);
  k_gemm_out<<<dim3(mt), dim3(256), 0, stream>>>(Ob, x, W2F, cvec, (float*)d_out, M);
}

// Round 6
// 402.106 us; speedup vs baseline: 1.1145x; 1.0720x over previous
//
#include <hip/hip_runtime.h>

typedef __bf16 bfrag __attribute__((ext_vector_type(8)));
typedef float f32x4 __attribute__((ext_vector_type(4)));

__device__ __forceinline__ unsigned short f2bf(float f) {
  unsigned u = __float_as_uint(f);
  u = (u + 0x7fffu + ((u >> 16) & 1u)) >> 16;
  return (unsigned short)u;
}
__device__ __forceinline__ float bflo(unsigned u) { return __uint_as_float(u << 16); }
__device__ __forceinline__ float bfhi(unsigned u) { return __uint_as_float(u & 0xffff0000u); }

// ---------------- weight prep: FRAGMENT-MAJOR layouts ----------------
__global__ void k_prep(const float* __restrict__ in_proj_w,
                       const float* __restrict__ conv_w,
                       const float* __restrict__ out_proj_w,
                       const float* __restrict__ out_proj_b,
                       const float* __restrict__ conv_b,
                       unsigned short* __restrict__ WcatF,
                       unsigned short* __restrict__ W2F,
                       float* __restrict__ cvec) {
  int b = blockIdx.x, t = threadIdx.x;
  if (b < 384) {
    unsigned short v = f2bf(in_proj_w[b * 128 + t]);
    int cb = b >> 7, r7 = b & 127;
    int cB = r7 >> 4, mr = r7 & 15;
    int ks = t >> 5, quad = (t >> 3) & 3, j = t & 7;
    WcatF[(((cb * 8 + cB) * 4 + ks) << 9) + (quad * 16 + mr) * 8 + j] = v;
    return;
  }
  const int c = b - 384;  // output channel (B-row), 128 blocks x 128 threads
  const int cB = c >> 4, mr = c & 15;
  __shared__ float cw[128];
  __shared__ float red[2];
  cw[t] = conv_w[(c * 128 + t) * 2 + 1];  // conv_w01 row c
  __syncthreads();

  float a[8] = {0.f, 0.f, 0.f, 0.f, 0.f, 0.f, 0.f, 0.f};
#pragma unroll
  for (int kk = 0; kk < 16; ++kk)
#pragma unroll
    for (int u = 0; u < 8; ++u)
      a[u] += cw[kk * 8 + u] * out_proj_w[(kk * 8 + u) * 128 + t];
  float s = ((a[0] + a[1]) + (a[2] + a[3])) + ((a[4] + a[5]) + (a[6] + a[7]));

  {  // K = t (W2 part)
    int kc = t >> 6, ks2 = (t >> 5) & 1, quad = (t >> 3) & 3, j = t & 7;
    W2F[(((cB * 4 + kc) * 2 + ks2) << 9) + (quad * 16 + mr) * 8 + j] = f2bf(s);
  }
  {  // K = 128 + t (W00 part)
    int K = 128 + t;
    int kc = K >> 6, ks2 = (K >> 5) & 1, quad = (K >> 3) & 3, j = K & 7;
    W2F[(((cB * 4 + kc) * 2 + ks2) << 9) + (quad * 16 + mr) * 8 + j] =
        f2bf(conv_w[(c * 128 + t) * 2]);
  }

  float p = cw[t] * out_proj_b[t];
#pragma unroll
  for (int d = 1; d < 64; d <<= 1) p += __shfl_xor(p, d);
  if ((t & 63) == 0) red[t >> 6] = p;
  __syncthreads();
  if (t == 0) cvec[c] = conv_b[c] + red[0] + red[1];
}

// ---------------- fused QKV GEMM: ZERO barriers, all frags direct ----------
__global__ __launch_bounds__(256, 4) void k_gemm_qkv(
    const float* __restrict__ x, const unsigned short* __restrict__ WcatF,
    const float* __restrict__ in_proj_b, unsigned short* __restrict__ Qb,
    unsigned short* __restrict__ KVb, int M) {
  __shared__ unsigned short se[4][32 * 72];  // wave-private transpose, 18.4 KB total
  const int m0 = blockIdx.x * 128;
  const int t = threadIdx.x;
  const int w = t >> 6, lane = t & 63, quad = lane >> 4, mr = lane & 15;
  unsigned short* sew = se[w];

  bfrag af[4][2];
#pragma unroll
  for (int ks = 0; ks < 4; ++ks)
#pragma unroll
    for (int r = 0; r < 2; ++r) {
      int row = m0 + w * 32 + r * 16 + mr;
      union { unsigned short s[8]; bfrag f; } u;
      if (row < M) {
        const float4* p =
            reinterpret_cast<const float4*>(&x[(size_t)row * 128 + ks * 32 + quad * 8]);
        float4 v0 = p[0], v1 = p[1];
        u.s[0] = f2bf(v0.x); u.s[1] = f2bf(v0.y); u.s[2] = f2bf(v0.z); u.s[3] = f2bf(v0.w);
        u.s[4] = f2bf(v1.x); u.s[5] = f2bf(v1.y); u.s[6] = f2bf(v1.z); u.s[7] = f2bf(v1.w);
      } else {
#pragma unroll
        for (int i = 0; i < 8; ++i) u.s[i] = 0;
      }
      af[ks][r] = u.f;
    }

#pragma unroll
  for (int cb = 0; cb < 3; ++cb) {
    unsigned short* dst = (cb == 0) ? Qb : KVb;
    const int ldst = (cb == 0) ? 128 : 256;
    const int cb_off = (cb == 2) ? 128 : 0;
#pragma unroll
    for (int half = 0; half < 2; ++half) {
      f32x4 acc[2][4];
#pragma unroll
      for (int r = 0; r < 2; ++r)
#pragma unroll
        for (int c = 0; c < 4; ++c) acc[r][c] = (f32x4){0.f, 0.f, 0.f, 0.f};
#pragma unroll
      for (int ks = 0; ks < 4; ++ks)
#pragma unroll
        for (int c = 0; c < 4; ++c) {
          union { uint4 v; bfrag f; } u;
          u.v = *reinterpret_cast<const uint4*>(
              &WcatF[(((cb * 8 + half * 4 + c) * 4 + ks) << 9) + lane * 8]);
          acc[0][c] = __builtin_amdgcn_mfma_f32_16x16x32_bf16(af[ks][0], u.f, acc[0][c], 0, 0, 0);
          acc[1][c] = __builtin_amdgcn_mfma_f32_16x16x32_bf16(af[ks][1], u.f, acc[1][c], 0, 0, 0);
        }
      const float* bias = in_proj_b + cb * 128 + half * 64;
#pragma unroll
      for (int r = 0; r < 2; ++r)
#pragma unroll
        for (int c = 0; c < 4; ++c) {
          float bv = bias[c * 16 + mr];
#pragma unroll
          for (int g = 0; g < 4; ++g)
            sew[(r * 16 + quad * 4 + g) * 72 + c * 16 + mr] = f2bf(acc[r][c][g] + bv);
        }
#pragma unroll
      for (int i = 0; i < 4; ++i) {
        int ch = i * 64 + lane;  // 256 chunks: 32 rows x 8 x 16B
        int row = ch >> 3, cp = ch & 7;
        int grow = m0 + w * 32 + row;
        if (grow < M) {
          uint4 v = *reinterpret_cast<const uint4*>(&sew[row * 72 + cp * 8]);
          *reinterpret_cast<uint4*>(
              &dst[(size_t)grow * ldst + cb_off + half * 64 + cp * 8]) = v;
        }
      }
    }
  }
}

// ------- FUSED attn + GEMM2 v2: 32-row blocks, occupancy-preserving --------
// R2's fusion failed on occupancy (34.8 KB LDS, 32 serial rows/wave). Here:
// 32-row tile per 256-thread block, 4 serial rows per half-wave, 18.4 KB LDS
// (O tile 8.7 KB, then reused as fp32 epilogue scratch), no min-blocks cap.
// Deletes the 101 MB Ob HBM round-trip and one dispatch. KVb must NOT alias
// out (concurrent random gathers vs out writes) -> KVb lives in workspace.
__global__ __launch_bounds__(256) void k_attn_out(
    const unsigned short* __restrict__ Qb, const unsigned short* __restrict__ KVb,
    const int* __restrict__ fn, const float* __restrict__ x,
    const unsigned short* __restrict__ W2F, const float* __restrict__ cvec,
    float* __restrict__ out, int M) {
  __shared__ char smem[18432];  // max(32*136*2, 4*32*36*4)
  unsigned short* Ow = reinterpret_cast<unsigned short*>(smem);  // [32][136]
  const int base = blockIdx.x * 32;
  const int t = threadIdx.x;
  const int w = t >> 6, lane = t & 63, quad = lane >> 4, mr = lane & 15;
  const int hf = lane >> 5, l5 = lane & 31;
  const float scale = 0.17677669529663687f;  // 1/sqrt(32)

  // ---- attn phase: half-wave per row, 4 rows each (v2 math, bitwise same) --
  for (int it = 0; it < 4; ++it) {
    const int ri = it * 8 + w * 2 + hf;
    const int n = base + ri;
    union { unsigned short s[4]; uint2 u; } pk;
    pk.u = make_uint2(0u, 0u);
    if (n < M) {  // uniform per 32-lane half; shuffles stay in 8-lane groups
      unsigned long long q8 = __builtin_nontemporal_load(
          reinterpret_cast<const unsigned long long*>(&Qb[(size_t)n * 128 + 4 * l5]));
      float q0 = bflo((unsigned)q8), q1 = bfhi((unsigned)q8);
      float q2 = bflo((unsigned)(q8 >> 32)), q3 = bfhi((unsigned)(q8 >> 32));
      int idx[8];
#pragma unroll
      for (int j = 0; j < 8; ++j)
        idx[j] = __builtin_nontemporal_load(&fn[n * 9 + 1 + j]);
      float o0 = 0.f, o1 = 0.f, o2 = 0.f, o3 = 0.f, sum = 0.f;
#pragma unroll
      for (int j = 0; j < 8; ++j) {
        bool valid = idx[j] < M;
        int id = valid ? idx[j] : 0;
        const unsigned short* rowp = &KVb[(size_t)id * 256 + 4 * l5];
        uint2 kk = *reinterpret_cast<const uint2*>(rowp);        // K cols 4*l5..+3
        uint2 vv = *reinterpret_cast<const uint2*>(rowp + 128);  // V cols 4*l5..+3
        float k0 = bflo(kk.x), k1 = bfhi(kk.x), k2 = bflo(kk.y), k3 = bfhi(kk.y);
        float p = q0 * k0 + q1 * k1 + q2 * k2 + q3 * k3;
        p += __shfl_xor(p, 1);
        p += __shfl_xor(p, 2);
        p += __shfl_xor(p, 4);  // per-head dot (8 lanes = 32 dims)
        float s = valid ? p * scale : -1e30f;
        float e = __expf(s);    // |s| << 88, no max-pass needed
        sum += e;
        float v0 = bflo(vv.x), v1 = bfhi(vv.x), v2 = bflo(vv.y), v3 = bfhi(vv.y);
        o0 += e * v0; o1 += e * v1; o2 += e * v2; o3 += e * v3;
      }
      float inv = 1.f / sum;
      pk.s[0] = f2bf(o0 * inv); pk.s[1] = f2bf(o1 * inv);
      pk.s[2] = f2bf(o2 * inv); pk.s[3] = f2bf(o3 * inv);
    }
    *reinterpret_cast<uint2*>(&Ow[ri * 136 + 4 * l5]) = pk.u;  // 256B contig
  }
  __syncthreads();  // O tile complete; GEMM reads all 32 rows cross-wave

  // ---- GEMM phase: out[base..base+32) = [O | x] @ [W2|W00]^T + cvec -------
  // Wave w owns cols w*32..w*32+31 (col-frags cB = w*2 + c2).
  f32x4 acc[2][2];
#pragma unroll
  for (int r = 0; r < 2; ++r)
#pragma unroll
    for (int c = 0; c < 2; ++c) acc[r][c] = (f32x4){0.f, 0.f, 0.f, 0.f};

#pragma unroll
  for (int kc = 0; kc < 4; ++kc) {
    bfrag af[2][2];
#pragma unroll
    for (int ks2 = 0; ks2 < 2; ++ks2)
#pragma unroll
      for (int r = 0; r < 2; ++r) {
        if (kc < 2) {  // O part from LDS (136-stride: conflict-free b128)
          union { uint4 v; bfrag f; } u;
          u.v = *reinterpret_cast<const uint4*>(
              &Ow[(r * 16 + mr) * 136 + kc * 64 + ks2 * 32 + quad * 8]);
          af[ks2][r] = u.f;
        } else {  // x part from global (same addrs all 4 waves -> L1 hits)
          int row = base + r * 16 + mr;
          union { unsigned short s[8]; bfrag f; } u;
          if (row < M) {
            const float4* p = reinterpret_cast<const float4*>(
                &x[(size_t)row * 128 + (kc - 2) * 64 + ks2 * 32 + quad * 8]);
            float4 v0 = p[0], v1 = p[1];
            u.s[0] = f2bf(v0.x); u.s[1] = f2bf(v0.y); u.s[2] = f2bf(v0.z); u.s[3] = f2bf(v0.w);
            u.s[4] = f2bf(v1.x); u.s[5] = f2bf(v1.y); u.s[6] = f2bf(v1.z); u.s[7] = f2bf(v1.w);
          } else {
#pragma unroll
            for (int i = 0; i < 8; ++i) u.s[i] = 0;
          }
          af[ks2][r] = u.f;
        }
      }
#pragma unroll
    for (int ks2 = 0; ks2 < 2; ++ks2)
#pragma unroll
      for (int c2 = 0; c2 < 2; ++c2) {
        union { uint4 v; bfrag f; } u;
        u.v = *reinterpret_cast<const uint4*>(
            &W2F[((((w * 2 + c2) * 4 + kc) * 2 + ks2) << 9) + lane * 8]);
        acc[0][c2] = __builtin_amdgcn_mfma_f32_16x16x32_bf16(af[ks2][0], u.f, acc[0][c2], 0, 0, 0);
        acc[1][c2] = __builtin_amdgcn_mfma_f32_16x16x32_bf16(af[ks2][1], u.f, acc[1][c2], 0, 0, 0);
      }
  }

  __syncthreads();  // all Ow reads done; reuse smem as fp32 scratch
  float* sfw = reinterpret_cast<float*>(smem) + w * (32 * 36);
#pragma unroll
  for (int c2 = 0; c2 < 2; ++c2) {
    float cv = cvec[(w * 2 + c2) * 16 + mr];
#pragma unroll
    for (int r = 0; r < 2; ++r)
#pragma unroll
      for (int g = 0; g < 4; ++g)
        sfw[(r * 16 + quad * 4 + g) * 36 + c2 * 16 + mr] = acc[r][c2][g] + cv;
  }
#pragma unroll
  for (int i = 0; i < 4; ++i) {
    int ch = i * 64 + lane;  // 256 chunks: 32 rows x 8 float4 (wave's 32 cols)
    int row = ch >> 3, c4 = ch & 7;
    int grow = base + row;
    if (grow < M) {
      float4 v = *reinterpret_cast<const float4*>(&sfw[row * 36 + c4 * 4]);
      *reinterpret_cast<float4*>(&out[(size_t)grow * 128 + w * 32 + c4 * 4]) = v;
    }
  }
}

// ---------------- legacy fallback kernels (workspace too small) ------------
__global__ __launch_bounds__(256) void k_attn(
    const unsigned short* __restrict__ Qb, const unsigned short* __restrict__ KVb,
    const int* __restrict__ fn, unsigned short* __restrict__ Ob, int M) {
  const int w = threadIdx.x >> 6, lane = threadIdx.x & 63;
  const int hf = lane >> 5, l5 = lane & 31;
  const int n = blockIdx.x * 8 + w * 2 + hf;
  if (n >= M) return;
  const float scale = 0.17677669529663687f;
  uint2 qp = *reinterpret_cast<const uint2*>(&Qb[(size_t)n * 128 + 4 * l5]);
  float q0 = bflo(qp.x), q1 = bfhi(qp.x), q2 = bflo(qp.y), q3 = bfhi(qp.y);
  int idx[8];
#pragma unroll
  for (int j = 0; j < 8; ++j) idx[j] = fn[n * 9 + 1 + j];
  float o0 = 0.f, o1 = 0.f, o2 = 0.f, o3 = 0.f, sum = 0.f;
#pragma unroll
  for (int j = 0; j < 8; ++j) {
    bool valid = idx[j] < M;
    int id = valid ? idx[j] : 0;
    const unsigned short* rowp = &KVb[(size_t)id * 256 + 4 * l5];
    uint2 kk = *reinterpret_cast<const uint2*>(rowp);
    uint2 vv = *reinterpret_cast<const uint2*>(rowp + 128);
    float k0 = bflo(kk.x), k1 = bfhi(kk.x), k2 = bflo(kk.y), k3 = bfhi(kk.y);
    float p = q0 * k0 + q1 * k1 + q2 * k2 + q3 * k3;
    p += __shfl_xor(p, 1);
    p += __shfl_xor(p, 2);
    p += __shfl_xor(p, 4);
    float s = valid ? p * scale : -1e30f;
    float e = __expf(s);
    sum += e;
    float v0 = bflo(vv.x), v1 = bfhi(vv.x), v2 = bflo(vv.y), v3 = bfhi(vv.y);
    o0 += e * v0; o1 += e * v1; o2 += e * v2; o3 += e * v3;
  }
  float inv = 1.f / sum;
  union { unsigned short s[4]; uint2 u; } pk;
  pk.s[0] = f2bf(o0 * inv); pk.s[1] = f2bf(o1 * inv);
  pk.s[2] = f2bf(o2 * inv); pk.s[3] = f2bf(o3 * inv);
  *reinterpret_cast<uint2*>(&Ob[(size_t)n * 128 + 4 * l5]) = pk.u;
}

__global__ __launch_bounds__(256, 4) void k_gemm_out(
    const unsigned short* __restrict__ Ob, const float* __restrict__ x,
    const unsigned short* __restrict__ W2F, const float* __restrict__ cvec,
    float* __restrict__ out, int M) {
  __shared__ float sf[4][32 * 36];
  const int m0 = blockIdx.x * 128;
  const int t = threadIdx.x;
  const int w = t >> 6, lane = t & 63, quad = lane >> 4, mr = lane & 15;
  float* sfw = sf[w];

  f32x4 acc[2][8];
#pragma unroll
  for (int r = 0; r < 2; ++r)
#pragma unroll
    for (int c = 0; c < 8; ++c) acc[r][c] = (f32x4){0.f, 0.f, 0.f, 0.f};

#pragma unroll
  for (int kc = 0; kc < 4; ++kc) {
    bfrag af[2][2];
#pragma unroll
    for (int ks2 = 0; ks2 < 2; ++ks2)
#pragma unroll
      for (int r = 0; r < 2; ++r) {
        int row = m0 + w * 32 + r * 16 + mr;
        if (kc < 2) {
          union { uint4 v; bfrag f; } u;
          u.v = make_uint4(0u, 0u, 0u, 0u);
          if (row < M)
            u.v = *reinterpret_cast<const uint4*>(
                &Ob[(size_t)row * 128 + kc * 64 + ks2 * 32 + quad * 8]);
          af[ks2][r] = u.f;
        } else {
          union { unsigned short s[8]; bfrag f; } u;
          if (row < M) {
            const float4* p = reinterpret_cast<const float4*>(
                &x[(size_t)row * 128 + (kc - 2) * 64 + ks2 * 32 + quad * 8]);
            float4 v0 = p[0], v1 = p[1];
            u.s[0] = f2bf(v0.x); u.s[1] = f2bf(v0.y); u.s[2] = f2bf(v0.z); u.s[3] = f2bf(v0.w);
            u.s[4] = f2bf(v1.x); u.s[5] = f2bf(v1.y); u.s[6] = f2bf(v1.z); u.s[7] = f2bf(v1.w);
          } else {
#pragma unroll
            for (int i = 0; i < 8; ++i) u.s[i] = 0;
          }
          af[ks2][r] = u.f;
        }
      }
#pragma unroll
    for (int ks2 = 0; ks2 < 2; ++ks2)
#pragma unroll
      for (int c = 0; c < 8; ++c) {
        union { uint4 v; bfrag f; } u;
        u.v = *reinterpret_cast<const uint4*>(
            &W2F[(((c * 4 + kc) * 2 + ks2) << 9) + lane * 8]);
        acc[0][c] = __builtin_amdgcn_mfma_f32_16x16x32_bf16(af[ks2][0], u.f, acc[0][c], 0, 0, 0);
        acc[1][c] = __builtin_amdgcn_mfma_f32_16x16x32_bf16(af[ks2][1], u.f, acc[1][c], 0, 0, 0);
      }
  }
#pragma unroll
  for (int p = 0; p < 4; ++p) {
#pragma unroll
    for (int cc = 0; cc < 2; ++cc) {
      int c = p * 2 + cc;
      float cv = cvec[c * 16 + mr];
#pragma unroll
      for (int r = 0; r < 2; ++r)
#pragma unroll
        for (int g = 0; g < 4; ++g)
          sfw[(r * 16 + quad * 4 + g) * 36 + cc * 16 + mr] = acc[r][c][g] + cv;
    }
#pragma unroll
    for (int i = 0; i < 4; ++i) {
      int ch = i * 64 + lane;
      int row = ch >> 3, c4 = ch & 7;
      int grow = m0 + w * 32 + row;
      if (grow < M) {
        float4 v = *reinterpret_cast<const float4*>(&sfw[row * 36 + c4 * 4]);
        *reinterpret_cast<float4*>(&out[(size_t)grow * 128 + p * 32 + c4 * 4]) = v;
      }
    }
  }
}

extern "C" void kernel_launch(void* const* d_in, const int* in_sizes, int n_in,
                              void* d_out, int out_size, void* d_ws, size_t ws_size,
                              hipStream_t stream) {
  const float* x          = (const float*)d_in[0];
  const int*   fn         = (const int*)d_in[1];
  const float* in_proj_w  = (const float*)d_in[4];
  const float* in_proj_b  = (const float*)d_in[5];
  const float* out_proj_w = (const float*)d_in[6];
  const float* out_proj_b = (const float*)d_in[7];
  const float* conv_w     = (const float*)d_in[8];
  const float* conv_b     = (const float*)d_in[9];
  const int M = in_sizes[0] / 128;
  const int mt = (M + 127) / 128;
  char* ws = (char*)d_ws;

  const size_t qbytes  = (size_t)M * 128 * 2;           // Qb
  const size_t kvbytes = (size_t)M * 256 * 2;           // KVb
  const size_t wbytes  = (size_t)(384 * 128 + 128 * 256) * 2 + 512;  // WcatF+W2F+cvec

  if (ws_size >= qbytes + kvbytes + wbytes) {
    // FUSED path (R2 proved ws_size fits): KVb in ws, O never touches HBM.
    unsigned short* Qb    = (unsigned short*)ws;
    unsigned short* KVb   = (unsigned short*)(ws + qbytes);
    unsigned short* WcatF = (unsigned short*)(ws + qbytes + kvbytes);
    unsigned short* W2F   = WcatF + 384 * 128;
    float*          cvec  = (float*)(W2F + 128 * 256);

    k_prep<<<dim3(512), dim3(128), 0, stream>>>(in_proj_w, conv_w, out_proj_w,
                                                out_proj_b, conv_b, WcatF, W2F, cvec);
    k_gemm_qkv<<<dim3(mt), dim3(256), 0, stream>>>(x, WcatF, in_proj_b, Qb, KVb, M);
    k_attn_out<<<dim3((M + 31) / 32), dim3(256), 0, stream>>>(
        Qb, KVb, fn, x, W2F, cvec, (float*)d_out, M);
  } else {
    // LEGACY path (R5-identical): KVb aliases d_out, separate attn + gemm_out.
    unsigned short* KVb   = (unsigned short*)d_out;
    unsigned short* Qb    = (unsigned short*)ws;
    unsigned short* Ob    = (unsigned short*)(ws + (size_t)M * 128 * 2);
    unsigned short* WcatF = (unsigned short*)(ws + (size_t)M * 128 * 4);
    unsigned short* W2F   = WcatF + 384 * 128;
    float*          cvec  = (float*)(W2F + 128 * 256);

    k_prep<<<dim3(512), dim3(128), 0, stream>>>(in_proj_w, conv_w, out_proj_w,
                                                out_proj_b, conv_b, WcatF, W2F, cvec);
    k_gemm_qkv<<<dim3(mt), dim3(256), 0, stream>>>(x, WcatF, in_proj_b, Qb, KVb, M);
    k_attn<<<dim3((M + 7) / 8), dim3(256), 0, stream>>>(Qb, KVb, fn, Ob, M);
    k_gemm_out<<<dim3(mt), dim3(256), 0, stream>>>(Ob, x, W2F, cvec, (float*)d_out, M);
  }
}

// Round 7
// 398.753 us; speedup vs baseline: 1.1239x; 1.0084x over previous
//
#include <hip/hip_runtime.h>

typedef __bf16 bfrag __attribute__((ext_vector_type(8)));
typedef float f32x4 __attribute__((ext_vector_type(4)));

__device__ __forceinline__ unsigned short f2bf(float f) {
  unsigned u = __float_as_uint(f);
  u = (u + 0x7fffu + ((u >> 16) & 1u)) >> 16;
  return (unsigned short)u;
}
__device__ __forceinline__ float bflo(unsigned u) { return __uint_as_float(u << 16); }
__device__ __forceinline__ float bfhi(unsigned u) { return __uint_as_float(u & 0xffff0000u); }

// ---------------- weight prep: FRAGMENT-MAJOR layouts ----------------
__global__ void k_prep(const float* __restrict__ in_proj_w,
                       const float* __restrict__ conv_w,
                       const float* __restrict__ out_proj_w,
                       const float* __restrict__ out_proj_b,
                       const float* __restrict__ conv_b,
                       unsigned short* __restrict__ WcatF,
                       unsigned short* __restrict__ W2F,
                       float* __restrict__ cvec) {
  int b = blockIdx.x, t = threadIdx.x;
  if (b < 384) {
    unsigned short v = f2bf(in_proj_w[b * 128 + t]);
    int cb = b >> 7, r7 = b & 127;
    int cB = r7 >> 4, mr = r7 & 15;
    int ks = t >> 5, quad = (t >> 3) & 3, j = t & 7;
    WcatF[(((cb * 8 + cB) * 4 + ks) << 9) + (quad * 16 + mr) * 8 + j] = v;
    return;
  }
  const int c = b - 384;  // output channel (B-row), 128 blocks x 128 threads
  const int cB = c >> 4, mr = c & 15;
  __shared__ float cw[128];
  __shared__ float red[2];
  cw[t] = conv_w[(c * 128 + t) * 2 + 1];  // conv_w01 row c
  __syncthreads();

  float a[8] = {0.f, 0.f, 0.f, 0.f, 0.f, 0.f, 0.f, 0.f};
#pragma unroll
  for (int kk = 0; kk < 16; ++kk)
#pragma unroll
    for (int u = 0; u < 8; ++u)
      a[u] += cw[kk * 8 + u] * out_proj_w[(kk * 8 + u) * 128 + t];
  float s = ((a[0] + a[1]) + (a[2] + a[3])) + ((a[4] + a[5]) + (a[6] + a[7]));

  {  // K = t (W2 part)
    int kc = t >> 6, ks2 = (t >> 5) & 1, quad = (t >> 3) & 3, j = t & 7;
    W2F[(((cB * 4 + kc) * 2 + ks2) << 9) + (quad * 16 + mr) * 8 + j] = f2bf(s);
  }
  {  // K = 128 + t (W00 part)
    int K = 128 + t;
    int kc = K >> 6, ks2 = (K >> 5) & 1, quad = (K >> 3) & 3, j = K & 7;
    W2F[(((cB * 4 + kc) * 2 + ks2) << 9) + (quad * 16 + mr) * 8 + j] =
        f2bf(conv_w[(c * 128 + t) * 2]);
  }

  float p = cw[t] * out_proj_b[t];
#pragma unroll
  for (int d = 1; d < 64; d <<= 1) p += __shfl_xor(p, d);
  if ((t & 63) == 0) red[t >> 6] = p;
  __syncthreads();
  if (t == 0) cvec[c] = conv_b[c] + red[0] + red[1];
}

// ---------------- K/V GEMM (fused path): Q dropped, KV only ---------------
// K,V -> KVb interleaved (row=256 ushort: K|V). Q is computed inside
// k_attn_out from the same x tile (deletes the 51 MB Qb round trip).
__global__ __launch_bounds__(256, 4) void k_gemm_kv(
    const float* __restrict__ x, const unsigned short* __restrict__ WcatF,
    const float* __restrict__ in_proj_b, unsigned short* __restrict__ KVb, int M) {
  __shared__ unsigned short se[4][32 * 72];  // wave-private transpose
  const int m0 = blockIdx.x * 128;
  const int t = threadIdx.x;
  const int w = t >> 6, lane = t & 63, quad = lane >> 4, mr = lane & 15;
  unsigned short* sew = se[w];

  bfrag af[4][2];
#pragma unroll
  for (int ks = 0; ks < 4; ++ks)
#pragma unroll
    for (int r = 0; r < 2; ++r) {
      int row = m0 + w * 32 + r * 16 + mr;
      union { unsigned short s[8]; bfrag f; } u;
      if (row < M) {
        const float4* p =
            reinterpret_cast<const float4*>(&x[(size_t)row * 128 + ks * 32 + quad * 8]);
        float4 v0 = p[0], v1 = p[1];
        u.s[0] = f2bf(v0.x); u.s[1] = f2bf(v0.y); u.s[2] = f2bf(v0.z); u.s[3] = f2bf(v0.w);
        u.s[4] = f2bf(v1.x); u.s[5] = f2bf(v1.y); u.s[6] = f2bf(v1.z); u.s[7] = f2bf(v1.w);
      } else {
#pragma unroll
        for (int i = 0; i < 8; ++i) u.s[i] = 0;
      }
      af[ks][r] = u.f;
    }

#pragma unroll
  for (int cb = 1; cb < 3; ++cb) {  // K (cb=1) and V (cb=2) only
    const int cb_off = (cb == 2) ? 128 : 0;
#pragma unroll
    for (int half = 0; half < 2; ++half) {
      f32x4 acc[2][4];
#pragma unroll
      for (int r = 0; r < 2; ++r)
#pragma unroll
        for (int c = 0; c < 4; ++c) acc[r][c] = (f32x4){0.f, 0.f, 0.f, 0.f};
#pragma unroll
      for (int ks = 0; ks < 4; ++ks)
#pragma unroll
        for (int c = 0; c < 4; ++c) {
          union { uint4 v; bfrag f; } u;
          u.v = *reinterpret_cast<const uint4*>(
              &WcatF[(((cb * 8 + half * 4 + c) * 4 + ks) << 9) + lane * 8]);
          acc[0][c] = __builtin_amdgcn_mfma_f32_16x16x32_bf16(af[ks][0], u.f, acc[0][c], 0, 0, 0);
          acc[1][c] = __builtin_amdgcn_mfma_f32_16x16x32_bf16(af[ks][1], u.f, acc[1][c], 0, 0, 0);
        }
      const float* bias = in_proj_b + cb * 128 + half * 64;
#pragma unroll
      for (int r = 0; r < 2; ++r)
#pragma unroll
        for (int c = 0; c < 4; ++c) {
          float bv = bias[c * 16 + mr];
#pragma unroll
          for (int g = 0; g < 4; ++g)
            sew[(r * 16 + quad * 4 + g) * 72 + c * 16 + mr] = f2bf(acc[r][c][g] + bv);
        }
#pragma unroll
      for (int i = 0; i < 4; ++i) {
        int ch = i * 64 + lane;  // 256 chunks: 32 rows x 8 x 16B
        int row = ch >> 3, cp = ch & 7;
        int grow = m0 + w * 32 + row;
        if (grow < M) {
          uint4 v = *reinterpret_cast<const uint4*>(&sew[row * 72 + cp * 8]);
          *reinterpret_cast<uint4*>(
              &KVb[(size_t)grow * 256 + cb_off + half * 64 + cp * 8]) = v;
        }
      }
    }
  }
}

// ------- FUSED Q-gen + attn + GEMM2: Q and O never touch HBM ---------------
// Phase 0: x tile (32 rows) -> bf16 A-frags, kept in regs for phases 1 AND 3.
// Phase 1: Q = x@Wq^T + bq via MFMA -> LDS (bitwise identical to old qkv Q).
// Phase 2: attention per half-wave (v2 math) reading Q from LDS -> O in LDS.
// Phase 3: out = [O | x] @ [W2|W00]^T + cvec; x-frags reused from phase 0.
__global__ __launch_bounds__(256) void k_attn_out(
    const unsigned short* __restrict__ KVb, const int* __restrict__ fn,
    const float* __restrict__ x, const unsigned short* __restrict__ WcatF,
    const float* __restrict__ in_proj_b, const unsigned short* __restrict__ W2F,
    const float* __restrict__ cvec, float* __restrict__ out, int M) {
  __shared__ char smem[18432];  // Q[32][136] + O[32][136] = 17.4KB; scratch 18KB
  unsigned short* Qw = reinterpret_cast<unsigned short*>(smem);            // [32][136]
  unsigned short* Ow = reinterpret_cast<unsigned short*>(smem) + 32 * 136; // [32][136]
  const int base = blockIdx.x * 32;
  const int t = threadIdx.x;
  const int w = t >> 6, lane = t & 63, quad = lane >> 4, mr = lane & 15;
  const int hf = lane >> 5, l5 = lane & 31;
  const float scale = 0.17677669529663687f;  // 1/sqrt(32)

  // ---- phase 0: x tile -> A-frags (one load serves Q-MFMA and W00-MFMA) ---
  bfrag af[4][2];
#pragma unroll
  for (int ks = 0; ks < 4; ++ks)
#pragma unroll
    for (int r = 0; r < 2; ++r) {
      int row = base + r * 16 + mr;
      union { unsigned short s[8]; bfrag f; } u;
      if (row < M) {
        const float4* p =
            reinterpret_cast<const float4*>(&x[(size_t)row * 128 + ks * 32 + quad * 8]);
        float4 v0 = p[0], v1 = p[1];
        u.s[0] = f2bf(v0.x); u.s[1] = f2bf(v0.y); u.s[2] = f2bf(v0.z); u.s[3] = f2bf(v0.w);
        u.s[4] = f2bf(v1.x); u.s[5] = f2bf(v1.y); u.s[6] = f2bf(v1.z); u.s[7] = f2bf(v1.w);
      } else {
#pragma unroll
        for (int i = 0; i < 8; ++i) u.s[i] = 0;
      }
      af[ks][r] = u.f;
    }

  // ---- phase 1: Q = x @ Wq^T + bq -> LDS (wave w owns cols w*32..+31) -----
  {
    f32x4 qacc[2][2];
#pragma unroll
    for (int r = 0; r < 2; ++r)
#pragma unroll
      for (int c2 = 0; c2 < 2; ++c2) qacc[r][c2] = (f32x4){0.f, 0.f, 0.f, 0.f};
#pragma unroll
    for (int ks = 0; ks < 4; ++ks)
#pragma unroll
      for (int c2 = 0; c2 < 2; ++c2) {
        union { uint4 v; bfrag f; } u;
        u.v = *reinterpret_cast<const uint4*>(
            &WcatF[((((w * 2 + c2) * 4) + ks) << 9) + lane * 8]);  // cb=0 frags
        qacc[0][c2] = __builtin_amdgcn_mfma_f32_16x16x32_bf16(af[ks][0], u.f, qacc[0][c2], 0, 0, 0);
        qacc[1][c2] = __builtin_amdgcn_mfma_f32_16x16x32_bf16(af[ks][1], u.f, qacc[1][c2], 0, 0, 0);
      }
#pragma unroll
    for (int c2 = 0; c2 < 2; ++c2) {
      float bv = in_proj_b[(w * 2 + c2) * 16 + mr];
#pragma unroll
      for (int r = 0; r < 2; ++r)
#pragma unroll
        for (int g = 0; g < 4; ++g)
          Qw[(r * 16 + quad * 4 + g) * 136 + (w * 2 + c2) * 16 + mr] =
              f2bf(qacc[r][c2][g] + bv);
    }
  }
  __syncthreads();  // Q tile complete

  // ---- phase 2: attention, half-wave per row, 4 rows each -----------------
  for (int it = 0; it < 4; ++it) {
    const int ri = it * 8 + w * 2 + hf;
    const int n = base + ri;
    union { unsigned short s[4]; uint2 u; } pk;
    pk.u = make_uint2(0u, 0u);
    if (n < M) {  // uniform per 32-lane half; shuffles stay in 8-lane groups
      uint2 qp = *reinterpret_cast<const uint2*>(&Qw[ri * 136 + 4 * l5]);
      float q0 = bflo(qp.x), q1 = bfhi(qp.x), q2 = bflo(qp.y), q3 = bfhi(qp.y);
      int idx[8];
#pragma unroll
      for (int j = 0; j < 8; ++j)
        idx[j] = __builtin_nontemporal_load(&fn[n * 9 + 1 + j]);
      float o0 = 0.f, o1 = 0.f, o2 = 0.f, o3 = 0.f, sum = 0.f;
#pragma unroll
      for (int j = 0; j < 8; ++j) {
        bool valid = idx[j] < M;
        int id = valid ? idx[j] : 0;
        const unsigned short* rowp = &KVb[(size_t)id * 256 + 4 * l5];
        uint2 kk = *reinterpret_cast<const uint2*>(rowp);        // K cols 4*l5..+3
        uint2 vv = *reinterpret_cast<const uint2*>(rowp + 128);  // V cols 4*l5..+3
        float k0 = bflo(kk.x), k1 = bfhi(kk.x), k2 = bflo(kk.y), k3 = bfhi(kk.y);
        float p = q0 * k0 + q1 * k1 + q2 * k2 + q3 * k3;
        p += __shfl_xor(p, 1);
        p += __shfl_xor(p, 2);
        p += __shfl_xor(p, 4);  // per-head dot (8 lanes = 32 dims)
        float s = valid ? p * scale : -1e30f;
        float e = __expf(s);    // |s| << 88, no max-pass needed
        sum += e;
        float v0 = bflo(vv.x), v1 = bfhi(vv.x), v2 = bflo(vv.y), v3 = bfhi(vv.y);
        o0 += e * v0; o1 += e * v1; o2 += e * v2; o3 += e * v3;
      }
      float inv = 1.f / sum;
      pk.s[0] = f2bf(o0 * inv); pk.s[1] = f2bf(o1 * inv);
      pk.s[2] = f2bf(o2 * inv); pk.s[3] = f2bf(o3 * inv);
    }
    *reinterpret_cast<uint2*>(&Ow[ri * 136 + 4 * l5]) = pk.u;  // 256B contig
  }
  __syncthreads();  // O tile complete; GEMM reads all 32 rows cross-wave

  // ---- phase 3: out[base..base+32) = [O | x] @ [W2|W00]^T + cvec ----------
  f32x4 acc[2][2];
#pragma unroll
  for (int r = 0; r < 2; ++r)
#pragma unroll
    for (int c = 0; c < 2; ++c) acc[r][c] = (f32x4){0.f, 0.f, 0.f, 0.f};

#pragma unroll
  for (int kc = 0; kc < 4; ++kc) {
    bfrag a2[2][2];
#pragma unroll
    for (int ks2 = 0; ks2 < 2; ++ks2)
#pragma unroll
      for (int r = 0; r < 2; ++r) {
        if (kc < 2) {  // O part from LDS (136-stride: conflict-free b128)
          union { uint4 v; bfrag f; } u;
          u.v = *reinterpret_cast<const uint4*>(
              &Ow[(r * 16 + mr) * 136 + kc * 64 + ks2 * 32 + quad * 8]);
          a2[ks2][r] = u.f;
        } else {  // x part: reuse phase-0 frags (no second x read)
          a2[ks2][r] = af[(kc - 2) * 2 + ks2][r];
        }
      }
#pragma unroll
    for (int ks2 = 0; ks2 < 2; ++ks2)
#pragma unroll
      for (int c2 = 0; c2 < 2; ++c2) {
        union { uint4 v; bfrag f; } u;
        u.v = *reinterpret_cast<const uint4*>(
            &W2F[((((w * 2 + c2) * 4 + kc) * 2 + ks2) << 9) + lane * 8]);
        acc[0][c2] = __builtin_amdgcn_mfma_f32_16x16x32_bf16(a2[ks2][0], u.f, acc[0][c2], 0, 0, 0);
        acc[1][c2] = __builtin_amdgcn_mfma_f32_16x16x32_bf16(a2[ks2][1], u.f, acc[1][c2], 0, 0, 0);
      }
  }

  __syncthreads();  // all Qw/Ow reads done; reuse smem as fp32 scratch
  float* sfw = reinterpret_cast<float*>(smem) + w * (32 * 36);
#pragma unroll
  for (int c2 = 0; c2 < 2; ++c2) {
    float cv = cvec[(w * 2 + c2) * 16 + mr];
#pragma unroll
    for (int r = 0; r < 2; ++r)
#pragma unroll
      for (int g = 0; g < 4; ++g)
        sfw[(r * 16 + quad * 4 + g) * 36 + c2 * 16 + mr] = acc[r][c2][g] + cv;
  }
#pragma unroll
  for (int i = 0; i < 4; ++i) {
    int ch = i * 64 + lane;  // 256 chunks: 32 rows x 8 float4 (wave's 32 cols)
    int row = ch >> 3, c4 = ch & 7;
    int grow = base + row;
    if (grow < M) {
      float4 v = *reinterpret_cast<const float4*>(&sfw[row * 36 + c4 * 4]);
      *reinterpret_cast<float4*>(&out[(size_t)grow * 128 + w * 32 + c4 * 4]) = v;
    }
  }
}

// ---------------- legacy fallback kernels (workspace too small) ------------
__global__ __launch_bounds__(256, 4) void k_gemm_qkv(
    const float* __restrict__ x, const unsigned short* __restrict__ WcatF,
    const float* __restrict__ in_proj_b, unsigned short* __restrict__ Qb,
    unsigned short* __restrict__ KVb, int M) {
  __shared__ unsigned short se[4][32 * 72];
  const int m0 = blockIdx.x * 128;
  const int t = threadIdx.x;
  const int w = t >> 6, lane = t & 63, quad = lane >> 4, mr = lane & 15;
  unsigned short* sew = se[w];

  bfrag af[4][2];
#pragma unroll
  for (int ks = 0; ks < 4; ++ks)
#pragma unroll
    for (int r = 0; r < 2; ++r) {
      int row = m0 + w * 32 + r * 16 + mr;
      union { unsigned short s[8]; bfrag f; } u;
      if (row < M) {
        const float4* p =
            reinterpret_cast<const float4*>(&x[(size_t)row * 128 + ks * 32 + quad * 8]);
        float4 v0 = p[0], v1 = p[1];
        u.s[0] = f2bf(v0.x); u.s[1] = f2bf(v0.y); u.s[2] = f2bf(v0.z); u.s[3] = f2bf(v0.w);
        u.s[4] = f2bf(v1.x); u.s[5] = f2bf(v1.y); u.s[6] = f2bf(v1.z); u.s[7] = f2bf(v1.w);
      } else {
#pragma unroll
        for (int i = 0; i < 8; ++i) u.s[i] = 0;
      }
      af[ks][r] = u.f;
    }

#pragma unroll
  for (int cb = 0; cb < 3; ++cb) {
    unsigned short* dst = (cb == 0) ? Qb : KVb;
    const int ldst = (cb == 0) ? 128 : 256;
    const int cb_off = (cb == 2) ? 128 : 0;
#pragma unroll
    for (int half = 0; half < 2; ++half) {
      f32x4 acc[2][4];
#pragma unroll
      for (int r = 0; r < 2; ++r)
#pragma unroll
        for (int c = 0; c < 4; ++c) acc[r][c] = (f32x4){0.f, 0.f, 0.f, 0.f};
#pragma unroll
      for (int ks = 0; ks < 4; ++ks)
#pragma unroll
        for (int c = 0; c < 4; ++c) {
          union { uint4 v; bfrag f; } u;
          u.v = *reinterpret_cast<const uint4*>(
              &WcatF[(((cb * 8 + half * 4 + c) * 4 + ks) << 9) + lane * 8]);
          acc[0][c] = __builtin_amdgcn_mfma_f32_16x16x32_bf16(af[ks][0], u.f, acc[0][c], 0, 0, 0);
          acc[1][c] = __builtin_amdgcn_mfma_f32_16x16x32_bf16(af[ks][1], u.f, acc[1][c], 0, 0, 0);
        }
      const float* bias = in_proj_b + cb * 128 + half * 64;
#pragma unroll
      for (int r = 0; r < 2; ++r)
#pragma unroll
        for (int c = 0; c < 4; ++c) {
          float bv = bias[c * 16 + mr];
#pragma unroll
          for (int g = 0; g < 4; ++g)
            sew[(r * 16 + quad * 4 + g) * 72 + c * 16 + mr] = f2bf(acc[r][c][g] + bv);
        }
#pragma unroll
      for (int i = 0; i < 4; ++i) {
        int ch = i * 64 + lane;
        int row = ch >> 3, cp = ch & 7;
        int grow = m0 + w * 32 + row;
        if (grow < M) {
          uint4 v = *reinterpret_cast<const uint4*>(&sew[row * 72 + cp * 8]);
          *reinterpret_cast<uint4*>(
              &dst[(size_t)grow * ldst + cb_off + half * 64 + cp * 8]) = v;
        }
      }
    }
  }
}

__global__ __launch_bounds__(256) void k_attn(
    const unsigned short* __restrict__ Qb, const unsigned short* __restrict__ KVb,
    const int* __restrict__ fn, unsigned short* __restrict__ Ob, int M) {
  const int w = threadIdx.x >> 6, lane = threadIdx.x & 63;
  const int hf = lane >> 5, l5 = lane & 31;
  const int n = blockIdx.x * 8 + w * 2 + hf;
  if (n >= M) return;
  const float scale = 0.17677669529663687f;
  uint2 qp = *reinterpret_cast<const uint2*>(&Qb[(size_t)n * 128 + 4 * l5]);
  float q0 = bflo(qp.x), q1 = bfhi(qp.x), q2 = bflo(qp.y), q3 = bfhi(qp.y);
  int idx[8];
#pragma unroll
  for (int j = 0; j < 8; ++j) idx[j] = fn[n * 9 + 1 + j];
  float o0 = 0.f, o1 = 0.f, o2 = 0.f, o3 = 0.f, sum = 0.f;
#pragma unroll
  for (int j = 0; j < 8; ++j) {
    bool valid = idx[j] < M;
    int id = valid ? idx[j] : 0;
    const unsigned short* rowp = &KVb[(size_t)id * 256 + 4 * l5];
    uint2 kk = *reinterpret_cast<const uint2*>(rowp);
    uint2 vv = *reinterpret_cast<const uint2*>(rowp + 128);
    float k0 = bflo(kk.x), k1 = bfhi(kk.x), k2 = bflo(kk.y), k3 = bfhi(kk.y);
    float p = q0 * k0 + q1 * k1 + q2 * k2 + q3 * k3;
    p += __shfl_xor(p, 1);
    p += __shfl_xor(p, 2);
    p += __shfl_xor(p, 4);
    float s = valid ? p * scale : -1e30f;
    float e = __expf(s);
    sum += e;
    float v0 = bflo(vv.x), v1 = bfhi(vv.x), v2 = bflo(vv.y), v3 = bfhi(vv.y);
    o0 += e * v0; o1 += e * v1; o2 += e * v2; o3 += e * v3;
  }
  float inv = 1.f / sum;
  union { unsigned short s[4]; uint2 u; } pk;
  pk.s[0] = f2bf(o0 * inv); pk.s[1] = f2bf(o1 * inv);
  pk.s[2] = f2bf(o2 * inv); pk.s[3] = f2bf(o3 * inv);
  *reinterpret_cast<uint2*>(&Ob[(size_t)n * 128 + 4 * l5]) = pk.u;
}

__global__ __launch_bounds__(256, 4) void k_gemm_out(
    const unsigned short* __restrict__ Ob, const float* __restrict__ x,
    const unsigned short* __restrict__ W2F, const float* __restrict__ cvec,
    float* __restrict__ out, int M) {
  __shared__ float sf[4][32 * 36];
  const int m0 = blockIdx.x * 128;
  const int t = threadIdx.x;
  const int w = t >> 6, lane = t & 63, quad = lane >> 4, mr = lane & 15;
  float* sfw = sf[w];

  f32x4 acc[2][8];
#pragma unroll
  for (int r = 0; r < 2; ++r)
#pragma unroll
    for (int c = 0; c < 8; ++c) acc[r][c] = (f32x4){0.f, 0.f, 0.f, 0.f};

#pragma unroll
  for (int kc = 0; kc < 4; ++kc) {
    bfrag af[2][2];
#pragma unroll
    for (int ks2 = 0; ks2 < 2; ++ks2)
#pragma unroll
      for (int r = 0; r < 2; ++r) {
        int row = m0 + w * 32 + r * 16 + mr;
        if (kc < 2) {
          union { uint4 v; bfrag f; } u;
          u.v = make_uint4(0u, 0u, 0u, 0u);
          if (row < M)
            u.v = *reinterpret_cast<const uint4*>(
                &Ob[(size_t)row * 128 + kc * 64 + ks2 * 32 + quad * 8]);
          af[ks2][r] = u.f;
        } else {
          union { unsigned short s[8]; bfrag f; } u;
          if (row < M) {
            const float4* p = reinterpret_cast<const float4*>(
                &x[(size_t)row * 128 + (kc - 2) * 64 + ks2 * 32 + quad * 8]);
            float4 v0 = p[0], v1 = p[1];
            u.s[0] = f2bf(v0.x); u.s[1] = f2bf(v0.y); u.s[2] = f2bf(v0.z); u.s[3] = f2bf(v0.w);
            u.s[4] = f2bf(v1.x); u.s[5] = f2bf(v1.y); u.s[6] = f2bf(v1.z); u.s[7] = f2bf(v1.w);
          } else {
#pragma unroll
            for (int i = 0; i < 8; ++i) u.s[i] = 0;
          }
          af[ks2][r] = u.f;
        }
      }
#pragma unroll
    for (int ks2 = 0; ks2 < 2; ++ks2)
#pragma unroll
      for (int c = 0; c < 8; ++c) {
        union { uint4 v; bfrag f; } u;
        u.v = *reinterpret_cast<const uint4*>(
            &W2F[(((c * 4 + kc) * 2 + ks2) << 9) + lane * 8]);
        acc[0][c] = __builtin_amdgcn_mfma_f32_16x16x32_bf16(af[ks2][0], u.f, acc[0][c], 0, 0, 0);
        acc[1][c] = __builtin_amdgcn_mfma_f32_16x16x32_bf16(af[ks2][1], u.f, acc[1][c], 0, 0, 0);
      }
  }
#pragma unroll
  for (int p = 0; p < 4; ++p) {
#pragma unroll
    for (int cc = 0; cc < 2; ++cc) {
      int c = p * 2 + cc;
      float cv = cvec[c * 16 + mr];
#pragma unroll
      for (int r = 0; r < 2; ++r)
#pragma unroll
        for (int g = 0; g < 4; ++g)
          sfw[(r * 16 + quad * 4 + g) * 36 + cc * 16 + mr] = acc[r][c][g] + cv;
    }
#pragma unroll
    for (int i = 0; i < 4; ++i) {
      int ch = i * 64 + lane;
      int row = ch >> 3, c4 = ch & 7;
      int grow = m0 + w * 32 + row;
      if (grow < M) {
        float4 v = *reinterpret_cast<const float4*>(&sfw[row * 36 + c4 * 4]);
        *reinterpret_cast<float4*>(&out[(size_t)grow * 128 + p * 32 + c4 * 4]) = v;
      }
    }
  }
}

extern "C" void kernel_launch(void* const* d_in, const int* in_sizes, int n_in,
                              void* d_out, int out_size, void* d_ws, size_t ws_size,
                              hipStream_t stream) {
  const float* x          = (const float*)d_in[0];
  const int*   fn         = (const int*)d_in[1];
  const float* in_proj_w  = (const float*)d_in[4];
  const float* in_proj_b  = (const float*)d_in[5];
  const float* out_proj_w = (const float*)d_in[6];
  const float* out_proj_b = (const float*)d_in[7];
  const float* conv_w     = (const float*)d_in[8];
  const float* conv_b     = (const float*)d_in[9];
  const int M = in_sizes[0] / 128;
  const int mt = (M + 127) / 128;
  char* ws = (char*)d_ws;

  const size_t kvbytes = (size_t)M * 256 * 2;           // KVb
  const size_t wbytes  = (size_t)(384 * 128 + 128 * 256) * 2 + 512;  // WcatF+W2F+cvec

  if (ws_size >= kvbytes + wbytes) {
    // FUSED path: Q computed in-kernel (no Qb), O stays in LDS, KVb in ws.
    unsigned short* KVb   = (unsigned short*)ws;
    unsigned short* WcatF = (unsigned short*)(ws + kvbytes);
    unsigned short* W2F   = WcatF + 384 * 128;
    float*          cvec  = (float*)(W2F + 128 * 256);

    k_prep<<<dim3(512), dim3(128), 0, stream>>>(in_proj_w, conv_w, out_proj_w,
                                                out_proj_b, conv_b, WcatF, W2F, cvec);
    k_gemm_kv<<<dim3(mt), dim3(256), 0, stream>>>(x, WcatF, in_proj_b, KVb, M);
    k_attn_out<<<dim3((M + 31) / 32), dim3(256), 0, stream>>>(
        KVb, fn, x, WcatF, in_proj_b, W2F, cvec, (float*)d_out, M);
  } else {
    // LEGACY path: KVb aliases d_out, separate qkv + attn + gemm_out.
    unsigned short* KVb   = (unsigned short*)d_out;
    unsigned short* Qb    = (unsigned short*)ws;
    unsigned short* Ob    = (unsigned short*)(ws + (size_t)M * 128 * 2);
    unsigned short* WcatF = (unsigned short*)(ws + (size_t)M * 128 * 4);
    unsigned short* W2F   = WcatF + 384 * 128;
    float*          cvec  = (float*)(W2F + 128 * 256);

    k_prep<<<dim3(512), dim3(128), 0, stream>>>(in_proj_w, conv_w, out_proj_w,
                                                out_proj_b, conv_b, WcatF, W2F, cvec);
    k_gemm_qkv<<<dim3(mt), dim3(256), 0, stream>>>(x, WcatF, in_proj_b, Qb, KVb, M);
    k_attn<<<dim3((M + 7) / 8), dim3(256), 0, stream>>>(Qb, KVb, fn, Ob, M);
    k_gemm_out<<<dim3(mt), dim3(256), 0, stream>>>(Ob, x, W2F, cvec, (float*)d_out, M);
  }
}